// Round 14
// baseline (137.708 us; speedup 1.0000x reference)
//
#include <hip/hip_runtime.h>
#include <hip/hip_fp16.h>

#define NN 50000
#define NE 800000
#define NB 16384

#define NBKT 784          // buckets of 64 node ids (784*64 = 50176 >= NN)
#define BCAP 1280         // per-bucket capacity (mean 1020, +8 sigma)
#define CAPL 8            // LDS staging depth per bucket per binning block
#define P1B  256          // binning blocks (1/CU) -> mean 4 entries/bucket/block
#define DNNB 256          // DNN gemm blocks (64 rows each) inside cntdis_dnn

typedef unsigned int uint;
typedef unsigned short ushort;

__device__ __forceinline__ uint pack2h(float a, float b) {
    return (uint)__half_as_ushort(__float2half_rn(a)) |
           ((uint)__half_as_ushort(__float2half_rn(b)) << 16);
}
__device__ __forceinline__ float h2f(ushort u) {
    return __half2float(__ushort_as_half(u));
}

// ---------------- zero the counters (runtime fill kernel is pathological) ------
__global__ void zero_kernel(int* __restrict__ p, int n)
{
    for (int i = threadIdx.x; i < n; i += 256) p[i] = 0;
}

// ---------------- fused dual binning: one pass over ei -------------------------
// entC = (r<<6)|(c&63) keyed by c>>6 ; entR = ((r&63)<<16)|c keyed by r>>6
__global__ __launch_bounds__(512) void binCR(const int* __restrict__ ei,
    uint* __restrict__ bufC, uint* __restrict__ bufR,
    int* __restrict__ gcurC, int* __restrict__ gcurR)
{
    __shared__ uint stC[NBKT * CAPL];           // 25 KiB
    __shared__ uint stR[NBKT * CAPL];           // 25 KiB
    __shared__ int lcC[NBKT], lcR[NBKT];
    const int tid = threadIdx.x;
    const int lane = tid & 63;
    const int wv = tid >> 6;                    // 0..7
    for (int i = tid; i < NBKT; i += 512) { lcC[i] = 0; lcR[i] = 0; }
    __syncthreads();
    const int per = (NE + P1B - 1) / P1B;
    const int lo = blockIdx.x * per;
    const int hi = (lo + per < NE) ? lo + per : NE;
    for (int e = lo + tid; e < hi; e += 512) {
        int r = ei[e], c = ei[NE + e];
        uint entC = ((uint)r << 6) | (uint)(c & 63);
        int b = c >> 6;
        int pos = atomicAdd(&lcC[b], 1);
        if (pos < CAPL) stC[b * CAPL + pos] = entC;
        else { int gp = atomicAdd(&gcurC[b], 1); bufC[(size_t)b * BCAP + gp] = entC; }
        uint entR = ((uint)(r & 63) << 16) | (uint)c;
        int rb = r >> 6;
        int pos2 = atomicAdd(&lcR[rb], 1);
        if (pos2 < CAPL) stR[rb * CAPL + pos2] = entR;
        else { int gp = atomicAdd(&gcurR[rb], 1); bufR[(size_t)rb * BCAP + gp] = entR; }
    }
    __syncthreads();
    // coalesced flush: 8 buckets per wave iteration, 8 lanes per bucket
    for (int base = wv * 8; base < NBKT; base += 64) {
        int wb = base + (lane >> 3);            // base<=776 -> wb<=783 always valid
        int idx = lane & 7;
        int n = lcC[wb]; if (n > CAPL) n = CAPL;
        int gb = 0;
        if (idx == 0 && n > 0) gb = atomicAdd(&gcurC[wb], n);
        gb = __shfl(gb, lane & 56);
        if (idx < n) bufC[(size_t)wb * BCAP + gb + idx] = stC[wb * CAPL + idx];
        int n2 = lcR[wb]; if (n2 > CAPL) n2 = CAPL;
        int gb2 = 0;
        if (idx == 0 && n2 > 0) gb2 = atomicAdd(&gcurR[wb], n2);
        gb2 = __shfl(gb2, lane & 56);
        if (idx < n2) bufR[(size_t)wb * BCAP + gb2 + idx] = stR[wb * CAPL + idx];
    }
}

// ---------------- cnt_dis + DNN gemm in one dispatch ---------------------------
// Blocks [0,256): DNN hdnn = x1 @ dnnW (64 rows, K=256 staged, BN fused).
// Blocks [256,1040): per-bucket in-degree histogram -> dis, cnth.
__global__ __launch_bounds__(256) void cntdis_dnn(
    const uint* __restrict__ bufC, const int* __restrict__ gcurC,
    float* __restrict__ dis, int* __restrict__ cnth,
    const float* __restrict__ X1, const float* __restrict__ Wd,
    float* __restrict__ H, float* __restrict__ bnsum,
    float* __restrict__ bnsumsq)
{
    __shared__ float xs[64 * 65];               // 16.25 KiB (DNN); aliased below
    const int tid = threadIdx.x;
    if (blockIdx.x >= DNNB) {
        // ---- cnt_dis for bucket bb ----
        int* hist = (int*)xs;
        const int bb = blockIdx.x - DNNB;
        if (tid < 64) hist[tid] = 0;
        __syncthreads();
        const int n = gcurC[bb];
        const uint* src = bufC + (size_t)bb * BCAP;
        for (int i = tid; i < n; i += 256) atomicAdd(&hist[src[i] & 63], 1);
        __syncthreads();
        if (tid < 64) {
            int c = bb * 64 + tid;
            cnth[bb * 64 + tid] = hist[tid];
            if (c < NN) dis[c] = rsqrtf((float)hist[tid] + 1.0f);
        }
        return;
    }
    // ---- DNN: 64 rows, K = 256 in 4 staged chunks, lane = row ----
    const int lane = tid & 63;
    const int wv = __builtin_amdgcn_readfirstlane(tid >> 6);   // 0..3
    const int c0 = wv * 16;
    const int row0 = blockIdx.x * 64;
    float acc[16];
#pragma unroll
    for (int j = 0; j < 16; ++j) acc[j] = 0.f;
#pragma unroll 1
    for (int chunk = 0; chunk < 4; ++chunk) {
        if (chunk) __syncthreads();
        for (int i = tid; i < 4096; i += 256) {
            int r = i >> 6, k = i & 63;
            xs[r * 65 + k] = X1[(size_t)(row0 + r) * 256 + chunk * 64 + k];
        }
        __syncthreads();
        const float* xrow = xs + lane * 65;
#pragma unroll
        for (int k4 = 0; k4 < 16; ++k4) {
            float x0 = xrow[4 * k4 + 0];
            float x1 = xrow[4 * k4 + 1];
            float x2 = xrow[4 * k4 + 2];
            float x3 = xrow[4 * k4 + 3];
            const float* wr = Wd + (size_t)(chunk * 64 + 4 * k4) * 64 + c0;
#pragma unroll
            for (int j = 0; j < 16; ++j) {
                float a = acc[j];
                a = fmaf(x0, wr[j],       a);
                a = fmaf(x1, wr[64 + j],  a);
                a = fmaf(x2, wr[128 + j], a);
                a = fmaf(x3, wr[192 + j], a);
                acc[j] = a;
            }
        }
    }
    __syncthreads();
#pragma unroll
    for (int j = 0; j < 16; ++j) xs[lane * 65 + c0 + j] = acc[j];
    __syncthreads();
    // coalesced store + fused BN partial (column = tid&63, constant per thread)
    float s = 0.f, q = 0.f;
    for (int i = tid; i < 4096; i += 256) {
        int r = i >> 6, c = i & 63;
        float v = xs[r * 65 + c];
        H[(size_t)(row0 + r) * 64 + c] = v;
        s += v; q += v * v;
    }
    __syncthreads();                             // xs free now
    float* red = xs;
    red[tid] = s; red[256 + tid] = q;
    __syncthreads();
    if (tid < 64) {
        atomicAdd(&bnsum[tid],  red[tid] + red[64+tid] + red[128+tid] + red[192+tid]);
        atomicAdd(&bnsumsq[tid], red[256+tid] + red[320+tid] + red[384+tid] + red[448+tid]);
    }
}

// ---------------- GCN1 GEMM, LDS-staged, uniform 784 blocks --------------------
// h1h = fp16(dis[row] * (x2 @ g1W)), K = 64, 64 rows/block, lane = row.
__global__ __launch_bounds__(256) void gcn_gemm(const float* __restrict__ X2,
    const float* __restrict__ W1, const float* __restrict__ dis,
    ushort* __restrict__ Hh)
{
    __shared__ float xs[64 * 65];               // 16.25 KiB
    const int tid = threadIdx.x;
    const int lane = tid & 63;
    const int wv = __builtin_amdgcn_readfirstlane(tid >> 6);   // 0..3
    const int c0 = wv * 16;
    const int row0 = blockIdx.x * 64;
    float acc[16];
#pragma unroll
    for (int j = 0; j < 16; ++j) acc[j] = 0.f;
    if (row0 + 64 <= NN) {
        for (int i = tid; i < 4096; i += 256) {
            int r = i >> 6, k = i & 63;
            xs[r * 65 + k] = X2[(size_t)(row0 + r) * 64 + k];
        }
    } else {
        for (int i = tid; i < 4096; i += 256) {
            int r = i >> 6, k = i & 63;
            xs[r * 65 + k] = (row0 + r < NN)
                           ? X2[(size_t)(row0 + r) * 64 + k] : 0.f;
        }
    }
    __syncthreads();
    const float* xrow = xs + lane * 65;
#pragma unroll
    for (int k4 = 0; k4 < 16; ++k4) {
        float x0 = xrow[4 * k4 + 0];
        float x1 = xrow[4 * k4 + 1];
        float x2 = xrow[4 * k4 + 2];
        float x3 = xrow[4 * k4 + 3];
        const float* wr = W1 + (size_t)(4 * k4) * 64 + c0;
#pragma unroll
        for (int j = 0; j < 16; ++j) {
            float a = acc[j];
            a = fmaf(x0, wr[j],       a);
            a = fmaf(x1, wr[64 + j],  a);
            a = fmaf(x2, wr[128 + j], a);
            a = fmaf(x3, wr[192 + j], a);
            acc[j] = a;
        }
    }
    __syncthreads();                             // xs reads done
#pragma unroll
    for (int j = 0; j < 16; ++j) xs[lane * 65 + c0 + j] = acc[j];
    __syncthreads();
    // coalesced fp16 store: tid-linear over 64 rows x 32 uint pairs
    for (int i = tid; i < 2048; i += 256) {
        int r = i >> 5, cp = (i & 31) * 2;
        int row = row0 + r;
        if (row < NN) {
            float d = dis[row];
            uint v = pack2h(d * xs[r * 65 + cp], d * xs[r * 65 + cp + 1]);
            *reinterpret_cast<uint*>(Hh + (size_t)row * 64 + cp) = v;
        }
    }
}

// ---------------- gather + fused wraw + node epilogue --------------------------
// w[r&63] = sum dis[c] over out-edges of r (row-bucket bb) ; then per node c:
// g_c = dis_c*(sum_in h1d_r + h1d_c) + b1 ; coef_c = dis_c*w_c + dis_c^2
__global__ __launch_bounds__(512) void gather_pass(const uint* __restrict__ bufC,
    const int* __restrict__ gcurC, const int* __restrict__ cnth,
    const uint* __restrict__ bufR, const int* __restrict__ gcurR,
    const float* __restrict__ dis, const ushort* __restrict__ hs,
    const float* __restrict__ b1, float* __restrict__ svec)
{
    __shared__ int sorted[BCAP];
    __shared__ int cntS[64], offsS[64], curS[64];
    __shared__ float w[64];
    __shared__ float red[8][64];
    const int tid = threadIdx.x;
    const int lane = tid & 63;
    const int wv = __builtin_amdgcn_readfirstlane(tid >> 6);   // 0..7
    const int bb = blockIdx.x;
    if (tid < 64) {                              // wave 0: load hist + 64-wide scan
        w[tid] = 0.f;
        int v = cnth[bb * 64 + tid];
        cntS[tid] = v;
        int s = v;
#pragma unroll
        for (int o = 1; o < 64; o <<= 1) {
            int u = __shfl_up(s, o);
            if (lane >= o) s += u;
        }
        offsS[tid] = s - v;
        curS[tid] = s - v;
    }
    __syncthreads();
    // wraw accumulation from the row-bucket (dis is a 200 KB L2-resident table)
    const int n2 = gcurR[bb];
    const uint* srcR = bufR + (size_t)bb * BCAP;
    for (int i = tid; i < n2; i += 512) {
        uint e = srcR[i];
        atomicAdd(&w[e >> 16], dis[e & 0xffffu]);
    }
    // LDS counting-sort scatter of the col-bucket
    const int n = gcurC[bb];
    const uint* src = bufC + (size_t)bb * BCAP;
    for (int i = tid; i < n; i += 512) {
        uint e = src[i];
        int p = atomicAdd(&curS[e & 63u], 1);
        sorted[p] = (int)(e >> 6);
    }
    __syncthreads();
    // each wave: 8 consecutive nodes, register accumulation, 8-deep load ILP
    float sacc = 0.f;
    const float bl = b1[lane];
#pragma unroll 1
    for (int t = 0; t < 8; ++t) {
        const int nd = wv * 8 + t;
        const int lo = offsS[nd], hi2 = lo + cntS[nd];
        float acc = 0.f;
        int e = lo;
        for (; e + 8 <= hi2; e += 8) {
            int r0 = sorted[e],     r1 = sorted[e + 1];
            int r2 = sorted[e + 2], r3 = sorted[e + 3];
            int r4 = sorted[e + 4], r5 = sorted[e + 5];
            int r6 = sorted[e + 6], r7 = sorted[e + 7];
            ushort u0 = hs[(size_t)r0 * 64 + lane];
            ushort u1 = hs[(size_t)r1 * 64 + lane];
            ushort u2 = hs[(size_t)r2 * 64 + lane];
            ushort u3 = hs[(size_t)r3 * 64 + lane];
            ushort u4 = hs[(size_t)r4 * 64 + lane];
            ushort u5 = hs[(size_t)r5 * 64 + lane];
            ushort u6 = hs[(size_t)r6 * 64 + lane];
            ushort u7 = hs[(size_t)r7 * 64 + lane];
            acc += ((h2f(u0) + h2f(u1)) + (h2f(u2) + h2f(u3))) +
                   ((h2f(u4) + h2f(u5)) + (h2f(u6) + h2f(u7)));
        }
        for (; e + 2 <= hi2; e += 2) {
            ushort u0 = hs[(size_t)sorted[e] * 64 + lane];
            ushort u1 = hs[(size_t)sorted[e + 1] * 64 + lane];
            acc += h2f(u0) + h2f(u1);
        }
        if (e < hi2) acc += h2f(hs[(size_t)sorted[e] * 64 + lane]);
        const int c = bb * 64 + nd;
        if (c < NN) {
            float d = dis[c];
            float g = fmaf(d, acc + h2f(hs[(size_t)c * 64 + lane]), bl);
            float coef = fmaf(d, w[nd], d * d);
            sacc += coef * fmaxf(g, 0.f);
        }
    }
    red[wv][lane] = sacc;
    __syncthreads();
    if (wv == 0) {
        float s = ((red[0][lane] + red[1][lane]) + (red[2][lane] + red[3][lane])) +
                  ((red[4][lane] + red[5][lane]) + (red[6][lane] + red[7][lane]));
        atomicAdd(&svec[lane], s);
    }
}

// ---------------- output + fused finalize --------------------------------------
__global__ __launch_bounds__(256) void out_final(const float* __restrict__ H,
    const float* __restrict__ bnsum, const float* __restrict__ bnsumsq,
    const float* __restrict__ gamma, const float* __restrict__ beta,
    const float* __restrict__ svec, const float* __restrict__ g2W,
    const float* __restrict__ g2b, const float* __restrict__ fc1W,
    const float* __restrict__ fc1b, const float* __restrict__ fc2W,
    const float* __restrict__ fc2b, float* __restrict__ out)
{
    __shared__ float scaleS[64], shiftS[64], vdnnS[64];
    __shared__ float consS;
    const int tid = threadIdx.x;
    const int lane = tid & 63;
    const int grp = tid >> 6;
    if (tid < 64) {                              // wave 0 computes finalize
        int j = tid;
        float mu = bnsum[j] * (1.0f / NB);
        float var = bnsumsq[j] * (1.0f / NB) - mu * mu;
        float sc = rsqrtf(var + 1e-5f) * gamma[j];
        scaleS[j] = sc;
        shiftS[j] = beta[j] - mu * sc;
        float ge = 0.f;
        for (int k = 0; k < 64; ++k) ge += svec[k] * g2W[k * 64 + j];
        ge = ge * (1.0f / NN) + g2b[j];
        float vd = 0.f, vg = 0.f;
        for (int k = 0; k < 64; ++k) {
            vd += fc1W[j * 64 + k] * fc2W[k];
            vg += fc1W[(64 + j) * 64 + k] * fc2W[k];
        }
        vdnnS[j] = vd;
        float part = ge * vg + fc1b[j] * fc2W[j];
#pragma unroll
        for (int o = 32; o > 0; o >>= 1) part += __shfl_down(part, o);
        if (j == 0) consS = part + fc2b[0];
    }
    __syncthreads();
    const float sc = scaleS[lane], sh = shiftS[lane], vd = vdnnS[lane];
    const float C = consS;
#pragma unroll 1
    for (int t = 0; t < 8; ++t) {
        int i = blockIdx.x * 32 + grp * 8 + t;
        float x = H[(size_t)i * 64 + lane] * sc + sh;
        x = fmaxf(x, 0.f) * vd;
#pragma unroll
        for (int o = 32; o > 0; o >>= 1) x += __shfl_down(x, o);
        if (lane == 0) out[i] = x + C;
    }
}

extern "C" void kernel_launch(void* const* d_in, const int* in_sizes, int n_in,
                              void* d_out, int out_size, void* d_ws, size_t ws_size,
                              hipStream_t stream)
{
    const float* x1    = (const float*)d_in[0];
    const float* x2    = (const float*)d_in[1];
    const int*   ei    = (const int*)d_in[2];
    const float* dnnW  = (const float*)d_in[3];
    // d_in[4] = dnn_b: cancels inside BatchNorm, unused
    const float* gamma = (const float*)d_in[5];
    const float* beta  = (const float*)d_in[6];
    const float* g1W   = (const float*)d_in[7];
    const float* g1b   = (const float*)d_in[8];
    const float* g2W   = (const float*)d_in[9];
    const float* g2b   = (const float*)d_in[10];
    const float* fc1W  = (const float*)d_in[11];
    const float* fc1b  = (const float*)d_in[12];
    const float* fc2W  = (const float*)d_in[13];
    const float* fc2b  = (const float*)d_in[14];

    float* ws      = (float*)d_ws;
    ushort* h1h    = (ushort*)ws;                 // 50176*64 ushorts = 1,605,632 f
    float* hdnn    = ws + 1605632;                // 1,048,576 f
    float* dis     = hdnn + 1048576;              // 50,176 f
    int*   cnth    = (int*)(dis + 50176 + 25088); // 50,176 i (keeps old layout)
    uint*  bufC    = (uint*)(cnth + 50176);       // 784*1280 = 1,003,520
    uint*  bufR    = bufC + NBKT * BCAP;          // 1,003,520
    int*   gcurC   = (int*)(bufR + NBKT * BCAP);  // 784   <- zero region start
    int*   gcurR   = gcurC + NBKT;                // 784
    float* bnsum   = (float*)(gcurR + NBKT);      // 64
    float* bnsumsq = bnsum + 64;                  // 64
    float* svec    = bnsumsq + 64;                // 64    <- zero region end (1760)

    zero_kernel<<<1, 256, 0, stream>>>(gcurC, NBKT * 2 + 192);

    binCR<<<P1B, 512, 0, stream>>>(ei, bufC, bufR, gcurC, gcurR);
    cntdis_dnn<<<DNNB + NBKT, 256, 0, stream>>>(bufC, gcurC, dis, cnth,
                                                x1, dnnW, hdnn, bnsum, bnsumsq);
    gcn_gemm<<<NBKT, 256, 0, stream>>>(x2, g1W, dis, h1h);
    gather_pass<<<NBKT, 512, 0, stream>>>(bufC, gcurC, cnth, bufR, gcurR,
                                          dis, h1h, g1b, svec);
    out_final<<<512, 256, 0, stream>>>(hdnn, bnsum, bnsumsq, gamma, beta, svec,
                                       g2W, g2b, fc1W, fc1b, fc2W, fc2b,
                                       (float*)d_out);
}

// Round 15
// 124.747 us; speedup vs baseline: 1.1039x; 1.1039x over previous
//
#include <hip/hip_runtime.h>
#include <hip/hip_fp16.h>

#define NN 50000
#define NE 800000
#define NB 16384

#define NBKT 784          // buckets of 64 node ids (784*64 = 50176 >= NN)
#define BCAP 1280         // per-bucket capacity (mean 1020, +8 sigma)
#define CAPL 8            // LDS staging depth per bucket per binning block
#define P1B  256          // binning blocks (1/CU) -> mean 4 entries/bucket/block
#define DNNB 256          // DNN gemm blocks (64 rows each) inside gather_dnn

typedef unsigned int uint;
typedef unsigned short ushort;

__device__ __forceinline__ uint pack2h(float a, float b) {
    return (uint)__half_as_ushort(__float2half_rn(a)) |
           ((uint)__half_as_ushort(__float2half_rn(b)) << 16);
}
__device__ __forceinline__ float h2f(ushort u) {
    return __half2float(__ushort_as_half(u));
}

// ---------------- zero the counters (runtime fill kernel is pathological) ------
__global__ void zero_kernel(int* __restrict__ p, int n)
{
    for (int i = threadIdx.x; i < n; i += 256) p[i] = 0;
}

// ---------------- fused dual binning: one pass over ei -------------------------
// entC = (r<<6)|(c&63) keyed by c>>6 ; entR = ((r&63)<<16)|c keyed by r>>6
__global__ __launch_bounds__(512) void binCR(const int* __restrict__ ei,
    uint* __restrict__ bufC, uint* __restrict__ bufR,
    int* __restrict__ gcurC, int* __restrict__ gcurR)
{
    __shared__ uint stC[NBKT * CAPL];           // 25 KiB
    __shared__ uint stR[NBKT * CAPL];           // 25 KiB
    __shared__ int lcC[NBKT], lcR[NBKT];
    const int tid = threadIdx.x;
    const int lane = tid & 63;
    const int wv = tid >> 6;                    // 0..7
    for (int i = tid; i < NBKT; i += 512) { lcC[i] = 0; lcR[i] = 0; }
    __syncthreads();
    const int per = (NE + P1B - 1) / P1B;
    const int lo = blockIdx.x * per;
    const int hi = (lo + per < NE) ? lo + per : NE;
    for (int e = lo + tid; e < hi; e += 512) {
        int r = ei[e], c = ei[NE + e];
        uint entC = ((uint)r << 6) | (uint)(c & 63);
        int b = c >> 6;
        int pos = atomicAdd(&lcC[b], 1);
        if (pos < CAPL) stC[b * CAPL + pos] = entC;
        else { int gp = atomicAdd(&gcurC[b], 1); bufC[(size_t)b * BCAP + gp] = entC; }
        uint entR = ((uint)(r & 63) << 16) | (uint)c;
        int rb = r >> 6;
        int pos2 = atomicAdd(&lcR[rb], 1);
        if (pos2 < CAPL) stR[rb * CAPL + pos2] = entR;
        else { int gp = atomicAdd(&gcurR[rb], 1); bufR[(size_t)rb * BCAP + gp] = entR; }
    }
    __syncthreads();
    // coalesced flush: 8 buckets per wave iteration, 8 lanes per bucket
    for (int base = wv * 8; base < NBKT; base += 64) {
        int wb = base + (lane >> 3);            // base<=776 -> wb<=783 always valid
        int idx = lane & 7;
        int n = lcC[wb]; if (n > CAPL) n = CAPL;
        int gb = 0;
        if (idx == 0 && n > 0) gb = atomicAdd(&gcurC[wb], n);
        gb = __shfl(gb, lane & 56);
        if (idx < n) bufC[(size_t)wb * BCAP + gb + idx] = stC[wb * CAPL + idx];
        int n2 = lcR[wb]; if (n2 > CAPL) n2 = CAPL;
        int gb2 = 0;
        if (idx == 0 && n2 > 0) gb2 = atomicAdd(&gcurR[wb], n2);
        gb2 = __shfl(gb2, lane & 56);
        if (idx < n2) bufR[(size_t)wb * BCAP + gb2 + idx] = stR[wb * CAPL + idx];
    }
}

// ---------------- per-bucket in-degree histogram -> dis, cnth ------------------
__global__ __launch_bounds__(256) void cnt_dis(const uint* __restrict__ bufC,
    const int* __restrict__ gcurC, float* __restrict__ dis,
    int* __restrict__ cnth)
{
    __shared__ int hist[64];
    const int tid = threadIdx.x, bb = blockIdx.x;
    if (tid < 64) hist[tid] = 0;
    __syncthreads();
    const int n = gcurC[bb];
    const uint* src = bufC + (size_t)bb * BCAP;
    for (int i = tid; i < n; i += 256) atomicAdd(&hist[src[i] & 63], 1);
    __syncthreads();
    if (tid < 64) {
        int c = bb * 64 + tid;
        cnth[bb * 64 + tid] = hist[tid];
        if (c < NN) dis[c] = rsqrtf((float)hist[tid] + 1.0f);
    }
}

// ---------------- GCN1 GEMM, LDS-staged, uniform 784 blocks --------------------
// h1h = fp16(dis[row] * (x2 @ g1W)), K = 64, 64 rows/block, lane = row.
__global__ __launch_bounds__(256) void gcn_gemm(const float* __restrict__ X2,
    const float* __restrict__ W1, const float* __restrict__ dis,
    ushort* __restrict__ Hh)
{
    __shared__ float xs[64 * 65];               // 16.25 KiB
    const int tid = threadIdx.x;
    const int lane = tid & 63;
    const int wv = __builtin_amdgcn_readfirstlane(tid >> 6);   // 0..3
    const int c0 = wv * 16;
    const int row0 = blockIdx.x * 64;
    float acc[16];
#pragma unroll
    for (int j = 0; j < 16; ++j) acc[j] = 0.f;
    if (row0 + 64 <= NN) {
        for (int i = tid; i < 4096; i += 256) {
            int r = i >> 6, k = i & 63;
            xs[r * 65 + k] = X2[(size_t)(row0 + r) * 64 + k];
        }
    } else {
        for (int i = tid; i < 4096; i += 256) {
            int r = i >> 6, k = i & 63;
            xs[r * 65 + k] = (row0 + r < NN)
                           ? X2[(size_t)(row0 + r) * 64 + k] : 0.f;
        }
    }
    __syncthreads();
    const float* xrow = xs + lane * 65;
#pragma unroll
    for (int k4 = 0; k4 < 16; ++k4) {
        float x0 = xrow[4 * k4 + 0];
        float x1 = xrow[4 * k4 + 1];
        float x2 = xrow[4 * k4 + 2];
        float x3 = xrow[4 * k4 + 3];
        const float* wr = W1 + (size_t)(4 * k4) * 64 + c0;
#pragma unroll
        for (int j = 0; j < 16; ++j) {
            float a = acc[j];
            a = fmaf(x0, wr[j],       a);
            a = fmaf(x1, wr[64 + j],  a);
            a = fmaf(x2, wr[128 + j], a);
            a = fmaf(x3, wr[192 + j], a);
            acc[j] = a;
        }
    }
    __syncthreads();                             // xs reads done
#pragma unroll
    for (int j = 0; j < 16; ++j) xs[lane * 65 + c0 + j] = acc[j];
    __syncthreads();
    // coalesced fp16 store: tid-linear over 64 rows x 32 uint pairs
    for (int i = tid; i < 2048; i += 256) {
        int r = i >> 5, cp = (i & 31) * 2;
        int row = row0 + r;
        if (row < NN) {
            float d = dis[row];
            uint v = pack2h(d * xs[r * 65 + cp], d * xs[r * 65 + cp + 1]);
            *reinterpret_cast<uint*>(Hh + (size_t)row * 64 + cp) = v;
        }
    }
}

// ---------------- gather + DNN gemm in one dispatch ----------------------------
// Blocks [0,256): DNN hdnn = x1 @ dnnW (64 rows, K=256 staged, 8 waves, BN
// fused). Blocks [256,1040): gather + wraw + node epilogue for bucket bb.
struct GatherSh {
    int sorted[BCAP];
    int cntS[64], offsS[64], curS[64];
    float w[64];
    float red[8][64];
};
union FusedSh {
    float xs[64 * 65];                          // DNN branch (16.64 KiB)
    GatherSh g;                                 // gather branch (~8.4 KiB)
};

__global__ __launch_bounds__(512) void gather_dnn(const uint* __restrict__ bufC,
    const int* __restrict__ gcurC, const int* __restrict__ cnth,
    const uint* __restrict__ bufR, const int* __restrict__ gcurR,
    const float* __restrict__ dis, const ushort* __restrict__ hs,
    const float* __restrict__ b1, float* __restrict__ svec,
    const float* __restrict__ X1, const float* __restrict__ Wd,
    float* __restrict__ H, float* __restrict__ bnsum,
    float* __restrict__ bnsumsq)
{
    __shared__ FusedSh sh;
    const int tid = threadIdx.x;
    const int lane = tid & 63;
    const int wv = __builtin_amdgcn_readfirstlane(tid >> 6);   // 0..7

    if (blockIdx.x < DNNB) {
        // ---- DNN: 64 rows, K = 256 in 4 staged chunks, lane = row, 8 waves ----
        float* xs = sh.xs;
        const int c0 = wv * 8;
        const int row0 = blockIdx.x * 64;
        float acc[8];
#pragma unroll
        for (int j = 0; j < 8; ++j) acc[j] = 0.f;
#pragma unroll 1
        for (int chunk = 0; chunk < 4; ++chunk) {
            if (chunk) __syncthreads();
            for (int i = tid; i < 4096; i += 512) {
                int r = i >> 6, k = i & 63;
                xs[r * 65 + k] = X1[(size_t)(row0 + r) * 256 + chunk * 64 + k];
            }
            __syncthreads();
            const float* xrow = xs + lane * 65;
#pragma unroll
            for (int k4 = 0; k4 < 16; ++k4) {
                float x0 = xrow[4 * k4 + 0];
                float x1 = xrow[4 * k4 + 1];
                float x2 = xrow[4 * k4 + 2];
                float x3 = xrow[4 * k4 + 3];
                const float* wr = Wd + (size_t)(chunk * 64 + 4 * k4) * 64 + c0;
#pragma unroll
                for (int j = 0; j < 8; ++j) {
                    float a = acc[j];
                    a = fmaf(x0, wr[j],       a);
                    a = fmaf(x1, wr[64 + j],  a);
                    a = fmaf(x2, wr[128 + j], a);
                    a = fmaf(x3, wr[192 + j], a);
                    acc[j] = a;
                }
            }
        }
        __syncthreads();
#pragma unroll
        for (int j = 0; j < 8; ++j) xs[lane * 65 + c0 + j] = acc[j];
        __syncthreads();
        // coalesced store + fused BN partial (col = tid&63, constant per thread)
        float s = 0.f, q = 0.f;
        for (int i = tid; i < 4096; i += 512) {
            int r = i >> 6, c = i & 63;
            float v = xs[r * 65 + c];
            H[(size_t)(row0 + r) * 64 + c] = v;
            s += v; q += v * v;
        }
        __syncthreads();                         // xs free now
        float* red = xs;
        red[tid] = s; red[512 + tid] = q;
        __syncthreads();
        if (tid < 64) {
            float ss = 0.f, qq = 0.f;
#pragma unroll
            for (int gidx = 0; gidx < 8; ++gidx) {
                ss += red[gidx * 64 + tid];
                qq += red[512 + gidx * 64 + tid];
            }
            atomicAdd(&bnsum[tid], ss);
            atomicAdd(&bnsumsq[tid], qq);
        }
        return;
    }

    // ---- gather for bucket bb ----
    const int bb = blockIdx.x - DNNB;
    GatherSh& G = sh.g;
    if (tid < 64) {                              // wave 0: load hist + 64-wide scan
        G.w[tid] = 0.f;
        int v = cnth[bb * 64 + tid];
        G.cntS[tid] = v;
        int s = v;
#pragma unroll
        for (int o = 1; o < 64; o <<= 1) {
            int u = __shfl_up(s, o);
            if (lane >= o) s += u;
        }
        G.offsS[tid] = s - v;
        G.curS[tid] = s - v;
    }
    __syncthreads();
    // wraw accumulation from the row-bucket (dis is a 200 KB L2-resident table)
    const int n2 = gcurR[bb];
    const uint* srcR = bufR + (size_t)bb * BCAP;
    for (int i = tid; i < n2; i += 512) {
        uint e = srcR[i];
        atomicAdd(&G.w[e >> 16], dis[e & 0xffffu]);
    }
    // LDS counting-sort scatter of the col-bucket
    const int n = gcurC[bb];
    const uint* src = bufC + (size_t)bb * BCAP;
    for (int i = tid; i < n; i += 512) {
        uint e = src[i];
        int p = atomicAdd(&G.curS[e & 63u], 1);
        G.sorted[p] = (int)(e >> 6);
    }
    __syncthreads();
    // each wave: 8 consecutive nodes, register accumulation, 8-deep load ILP
    float sacc = 0.f;
    const float bl = b1[lane];
#pragma unroll 1
    for (int t = 0; t < 8; ++t) {
        const int nd = wv * 8 + t;
        const int lo = G.offsS[nd], hi2 = lo + G.cntS[nd];
        float acc = 0.f;
        int e = lo;
        for (; e + 8 <= hi2; e += 8) {
            int r0 = G.sorted[e],     r1 = G.sorted[e + 1];
            int r2 = G.sorted[e + 2], r3 = G.sorted[e + 3];
            int r4 = G.sorted[e + 4], r5 = G.sorted[e + 5];
            int r6 = G.sorted[e + 6], r7 = G.sorted[e + 7];
            ushort u0 = hs[(size_t)r0 * 64 + lane];
            ushort u1 = hs[(size_t)r1 * 64 + lane];
            ushort u2 = hs[(size_t)r2 * 64 + lane];
            ushort u3 = hs[(size_t)r3 * 64 + lane];
            ushort u4 = hs[(size_t)r4 * 64 + lane];
            ushort u5 = hs[(size_t)r5 * 64 + lane];
            ushort u6 = hs[(size_t)r6 * 64 + lane];
            ushort u7 = hs[(size_t)r7 * 64 + lane];
            acc += ((h2f(u0) + h2f(u1)) + (h2f(u2) + h2f(u3))) +
                   ((h2f(u4) + h2f(u5)) + (h2f(u6) + h2f(u7)));
        }
        for (; e + 2 <= hi2; e += 2) {
            ushort u0 = hs[(size_t)G.sorted[e] * 64 + lane];
            ushort u1 = hs[(size_t)G.sorted[e + 1] * 64 + lane];
            acc += h2f(u0) + h2f(u1);
        }
        if (e < hi2) acc += h2f(hs[(size_t)G.sorted[e] * 64 + lane]);
        const int c = bb * 64 + nd;
        if (c < NN) {
            float d = dis[c];
            float g = fmaf(d, acc + h2f(hs[(size_t)c * 64 + lane]), bl);
            float coef = fmaf(d, G.w[nd], d * d);
            sacc += coef * fmaxf(g, 0.f);
        }
    }
    G.red[wv][lane] = sacc;
    __syncthreads();
    if (wv == 0) {
        float s = ((G.red[0][lane] + G.red[1][lane]) + (G.red[2][lane] + G.red[3][lane])) +
                  ((G.red[4][lane] + G.red[5][lane]) + (G.red[6][lane] + G.red[7][lane]));
        atomicAdd(&svec[lane], s);
    }
}

// ---------------- output + fused finalize --------------------------------------
__global__ __launch_bounds__(256) void out_final(const float* __restrict__ H,
    const float* __restrict__ bnsum, const float* __restrict__ bnsumsq,
    const float* __restrict__ gamma, const float* __restrict__ beta,
    const float* __restrict__ svec, const float* __restrict__ g2W,
    const float* __restrict__ g2b, const float* __restrict__ fc1W,
    const float* __restrict__ fc1b, const float* __restrict__ fc2W,
    const float* __restrict__ fc2b, float* __restrict__ out)
{
    __shared__ float scaleS[64], shiftS[64], vdnnS[64];
    __shared__ float consS;
    const int tid = threadIdx.x;
    const int lane = tid & 63;
    const int grp = tid >> 6;
    if (tid < 64) {                              // wave 0 computes finalize
        int j = tid;
        float mu = bnsum[j] * (1.0f / NB);
        float var = bnsumsq[j] * (1.0f / NB) - mu * mu;
        float sc = rsqrtf(var + 1e-5f) * gamma[j];
        scaleS[j] = sc;
        shiftS[j] = beta[j] - mu * sc;
        float ge = 0.f;
        for (int k = 0; k < 64; ++k) ge += svec[k] * g2W[k * 64 + j];
        ge = ge * (1.0f / NN) + g2b[j];
        float vd = 0.f, vg = 0.f;
        for (int k = 0; k < 64; ++k) {
            vd += fc1W[j * 64 + k] * fc2W[k];
            vg += fc1W[(64 + j) * 64 + k] * fc2W[k];
        }
        vdnnS[j] = vd;
        float part = ge * vg + fc1b[j] * fc2W[j];
#pragma unroll
        for (int o = 32; o > 0; o >>= 1) part += __shfl_down(part, o);
        if (j == 0) consS = part + fc2b[0];
    }
    __syncthreads();
    const float sc = scaleS[lane], sh = shiftS[lane], vd = vdnnS[lane];
    const float C = consS;
#pragma unroll 1
    for (int t = 0; t < 8; ++t) {
        int i = blockIdx.x * 32 + grp * 8 + t;
        float x = H[(size_t)i * 64 + lane] * sc + sh;
        x = fmaxf(x, 0.f) * vd;
#pragma unroll
        for (int o = 32; o > 0; o >>= 1) x += __shfl_down(x, o);
        if (lane == 0) out[i] = x + C;
    }
}

extern "C" void kernel_launch(void* const* d_in, const int* in_sizes, int n_in,
                              void* d_out, int out_size, void* d_ws, size_t ws_size,
                              hipStream_t stream)
{
    const float* x1    = (const float*)d_in[0];
    const float* x2    = (const float*)d_in[1];
    const int*   ei    = (const int*)d_in[2];
    const float* dnnW  = (const float*)d_in[3];
    // d_in[4] = dnn_b: cancels inside BatchNorm, unused
    const float* gamma = (const float*)d_in[5];
    const float* beta  = (const float*)d_in[6];
    const float* g1W   = (const float*)d_in[7];
    const float* g1b   = (const float*)d_in[8];
    const float* g2W   = (const float*)d_in[9];
    const float* g2b   = (const float*)d_in[10];
    const float* fc1W  = (const float*)d_in[11];
    const float* fc1b  = (const float*)d_in[12];
    const float* fc2W  = (const float*)d_in[13];
    const float* fc2b  = (const float*)d_in[14];

    float* ws      = (float*)d_ws;
    ushort* h1h    = (ushort*)ws;                 // 50176*64 ushorts = 1,605,632 f
    float* hdnn    = ws + 1605632;                // 1,048,576 f
    float* dis     = hdnn + 1048576;              // 50,176 f
    int*   cnth    = (int*)(dis + 50176 + 25088); // 50,176 i (keeps old layout)
    uint*  bufC    = (uint*)(cnth + 50176);       // 784*1280 = 1,003,520
    uint*  bufR    = bufC + NBKT * BCAP;          // 1,003,520
    int*   gcurC   = (int*)(bufR + NBKT * BCAP);  // 784   <- zero region start
    int*   gcurR   = gcurC + NBKT;                // 784
    float* bnsum   = (float*)(gcurR + NBKT);      // 64
    float* bnsumsq = bnsum + 64;                  // 64
    float* svec    = bnsumsq + 64;                // 64    <- zero region end (1760)

    zero_kernel<<<1, 256, 0, stream>>>(gcurC, NBKT * 2 + 192);

    binCR<<<P1B, 512, 0, stream>>>(ei, bufC, bufR, gcurC, gcurR);
    cnt_dis<<<NBKT, 256, 0, stream>>>(bufC, gcurC, dis, cnth);
    gcn_gemm<<<NBKT, 256, 0, stream>>>(x2, g1W, dis, h1h);
    gather_dnn<<<DNNB + NBKT, 512, 0, stream>>>(bufC, gcurC, cnth, bufR, gcurR,
                                                dis, h1h, g1b, svec,
                                                x1, dnnW, hdnn, bnsum, bnsumsq);
    out_final<<<512, 256, 0, stream>>>(hdnn, bnsum, bnsumsq, gamma, beta, svec,
                                       g2W, g2b, fc1W, fc1b, fc2W, fc2b,
                                       (float*)d_out);
}

// Round 16
// 117.582 us; speedup vs baseline: 1.1712x; 1.0609x over previous
//
#include <hip/hip_runtime.h>
#include <hip/hip_fp16.h>

#define NN 50000
#define NE 800000
#define NB 16384

#define NBKT 784          // buckets of 64 node ids (784*64 = 50176 >= NN)
#define BCAP 1280         // per-bucket capacity (mean 1020, +8 sigma)
#define CAPL 8            // LDS staging depth per bucket per binning block
#define P1B  256          // binning blocks (1/CU) -> mean 4 entries/bucket/block
#define DNNB 256          // DNN gemm blocks (64 rows each) inside gather_dnn

typedef unsigned int uint;
typedef unsigned short ushort;

__device__ __forceinline__ uint pack2h(float a, float b) {
    return (uint)__half_as_ushort(__float2half_rn(a)) |
           ((uint)__half_as_ushort(__float2half_rn(b)) << 16);
}
__device__ __forceinline__ float h2f(ushort u) {
    return __half2float(__ushort_as_half(u));
}

// ---------------- zero the counters (runtime fill kernel is pathological) ------
__global__ void zero_kernel(int* __restrict__ p, int n)
{
    for (int i = threadIdx.x; i < n; i += 256) p[i] = 0;
}

// ---------------- fused dual binning: one pass over ei -------------------------
// entC = (r<<6)|(c&63) keyed by c>>6 ; entR = ((r&63)<<16)|c keyed by r>>6
__global__ __launch_bounds__(512) void binCR(const int* __restrict__ ei,
    uint* __restrict__ bufC, uint* __restrict__ bufR,
    int* __restrict__ gcurC, int* __restrict__ gcurR)
{
    __shared__ uint stC[NBKT * CAPL];           // 25 KiB
    __shared__ uint stR[NBKT * CAPL];           // 25 KiB
    __shared__ int lcC[NBKT], lcR[NBKT];
    const int tid = threadIdx.x;
    const int lane = tid & 63;
    const int wv = tid >> 6;                    // 0..7
    for (int i = tid; i < NBKT; i += 512) { lcC[i] = 0; lcR[i] = 0; }
    __syncthreads();
    const int per = (NE + P1B - 1) / P1B;
    const int lo = blockIdx.x * per;
    const int hi = (lo + per < NE) ? lo + per : NE;
    for (int e = lo + tid; e < hi; e += 512) {
        int r = ei[e], c = ei[NE + e];
        uint entC = ((uint)r << 6) | (uint)(c & 63);
        int b = c >> 6;
        int pos = atomicAdd(&lcC[b], 1);
        if (pos < CAPL) stC[b * CAPL + pos] = entC;
        else { int gp = atomicAdd(&gcurC[b], 1); bufC[(size_t)b * BCAP + gp] = entC; }
        uint entR = ((uint)(r & 63) << 16) | (uint)c;
        int rb = r >> 6;
        int pos2 = atomicAdd(&lcR[rb], 1);
        if (pos2 < CAPL) stR[rb * CAPL + pos2] = entR;
        else { int gp = atomicAdd(&gcurR[rb], 1); bufR[(size_t)rb * BCAP + gp] = entR; }
    }
    __syncthreads();
    // coalesced flush: 8 buckets per wave iteration, 8 lanes per bucket
    for (int base = wv * 8; base < NBKT; base += 64) {
        int wb = base + (lane >> 3);            // base<=776 -> wb<=783 always valid
        int idx = lane & 7;
        int n = lcC[wb]; if (n > CAPL) n = CAPL;
        int gb = 0;
        if (idx == 0 && n > 0) gb = atomicAdd(&gcurC[wb], n);
        gb = __shfl(gb, lane & 56);
        if (idx < n) bufC[(size_t)wb * BCAP + gb + idx] = stC[wb * CAPL + idx];
        int n2 = lcR[wb]; if (n2 > CAPL) n2 = CAPL;
        int gb2 = 0;
        if (idx == 0 && n2 > 0) gb2 = atomicAdd(&gcurR[wb], n2);
        gb2 = __shfl(gb2, lane & 56);
        if (idx < n2) bufR[(size_t)wb * BCAP + gb2 + idx] = stR[wb * CAPL + idx];
    }
}

// ---------------- GCN1 GEMM + fused cnt_dis, uniform 784 blocks ----------------
// Block bb: (1) histogram bucket bb -> cnth, dis (these are exactly this
// block's 64 rows); (2) h1h = fp16(dis[row] * (x2 @ g1W)), K=64, lane = row.
__global__ __launch_bounds__(256) void gcn_gemm(const uint* __restrict__ bufC,
    const int* __restrict__ gcurC, const float* __restrict__ X2,
    const float* __restrict__ W1, ushort* __restrict__ Hh,
    float* __restrict__ dis, int* __restrict__ cnth)
{
    __shared__ float xs[64 * 65];               // 16.25 KiB
    __shared__ int hist[64];
    __shared__ float disS[64];
    const int tid = threadIdx.x;
    const int lane = tid & 63;
    const int wv = __builtin_amdgcn_readfirstlane(tid >> 6);   // 0..3
    const int c0 = wv * 16;
    const int bb = blockIdx.x;
    const int row0 = bb * 64;
    // ---- phase 0: per-bucket in-degree histogram -> dis, cnth ----
    if (tid < 64) hist[tid] = 0;
    __syncthreads();
    const int nb = gcurC[bb];
    const uint* srcb = bufC + (size_t)bb * BCAP;
    for (int i = tid; i < nb; i += 256) atomicAdd(&hist[srcb[i] & 63], 1);
    __syncthreads();
    if (tid < 64) {
        int c = row0 + tid;
        cnth[row0 + tid] = hist[tid];
        float d = rsqrtf((float)hist[tid] + 1.0f);
        disS[tid] = d;
        if (c < NN) dis[c] = d;
    }
    // ---- phase 1: GEMM ----
    float acc[16];
#pragma unroll
    for (int j = 0; j < 16; ++j) acc[j] = 0.f;
    if (row0 + 64 <= NN) {
        for (int i = tid; i < 4096; i += 256) {
            int r = i >> 6, k = i & 63;
            xs[r * 65 + k] = X2[(size_t)(row0 + r) * 64 + k];
        }
    } else {
        for (int i = tid; i < 4096; i += 256) {
            int r = i >> 6, k = i & 63;
            xs[r * 65 + k] = (row0 + r < NN)
                           ? X2[(size_t)(row0 + r) * 64 + k] : 0.f;
        }
    }
    __syncthreads();
    const float* xrow = xs + lane * 65;
#pragma unroll
    for (int k4 = 0; k4 < 16; ++k4) {
        float x0 = xrow[4 * k4 + 0];
        float x1 = xrow[4 * k4 + 1];
        float x2 = xrow[4 * k4 + 2];
        float x3 = xrow[4 * k4 + 3];
        const float* wr = W1 + (size_t)(4 * k4) * 64 + c0;
#pragma unroll
        for (int j = 0; j < 16; ++j) {
            float a = acc[j];
            a = fmaf(x0, wr[j],       a);
            a = fmaf(x1, wr[64 + j],  a);
            a = fmaf(x2, wr[128 + j], a);
            a = fmaf(x3, wr[192 + j], a);
            acc[j] = a;
        }
    }
    __syncthreads();                             // xs reads done
#pragma unroll
    for (int j = 0; j < 16; ++j) xs[lane * 65 + c0 + j] = acc[j];
    __syncthreads();
    // coalesced fp16 store: tid-linear over 64 rows x 32 uint pairs
    for (int i = tid; i < 2048; i += 256) {
        int r = i >> 5, cp = (i & 31) * 2;
        int row = row0 + r;
        if (row < NN) {
            float d = disS[r];
            uint v = pack2h(d * xs[r * 65 + cp], d * xs[r * 65 + cp + 1]);
            *reinterpret_cast<uint*>(Hh + (size_t)row * 64 + cp) = v;
        }
    }
}

// ---------------- gather + DNN gemm in one dispatch ----------------------------
// Blocks [0,256): DNN hdnn = x1 @ dnnW (64 rows, K=256 staged, 8 waves, BN
// fused). Blocks [256,1040): gather (4 edges/VMEM-instr) + wraw + epilogue.
struct GatherSh {
    int sorted[BCAP];
    int cntS[64], offsS[64], curS[64];
    float w[64];
    float red[8][64];
};
union FusedSh {
    float xs[64 * 65];                          // DNN branch (16.64 KiB)
    GatherSh g;                                 // gather branch (~8.4 KiB)
};

__global__ __launch_bounds__(512) void gather_dnn(const uint* __restrict__ bufC,
    const int* __restrict__ gcurC, const int* __restrict__ cnth,
    const uint* __restrict__ bufR, const int* __restrict__ gcurR,
    const float* __restrict__ dis, const ushort* __restrict__ hs,
    const float* __restrict__ b1, float* __restrict__ svec,
    const float* __restrict__ X1, const float* __restrict__ Wd,
    float* __restrict__ H, float* __restrict__ bnsum,
    float* __restrict__ bnsumsq)
{
    __shared__ FusedSh sh;
    const int tid = threadIdx.x;
    const int lane = tid & 63;
    const int wv = __builtin_amdgcn_readfirstlane(tid >> 6);   // 0..7

    if (blockIdx.x < DNNB) {
        // ---- DNN: 64 rows, K = 256 in 4 staged chunks, lane = row, 8 waves ----
        float* xs = sh.xs;
        const int c0 = wv * 8;
        const int row0 = blockIdx.x * 64;
        float acc[8];
#pragma unroll
        for (int j = 0; j < 8; ++j) acc[j] = 0.f;
#pragma unroll 1
        for (int chunk = 0; chunk < 4; ++chunk) {
            if (chunk) __syncthreads();
            for (int i = tid; i < 4096; i += 512) {
                int r = i >> 6, k = i & 63;
                xs[r * 65 + k] = X1[(size_t)(row0 + r) * 256 + chunk * 64 + k];
            }
            __syncthreads();
            const float* xrow = xs + lane * 65;
#pragma unroll
            for (int k4 = 0; k4 < 16; ++k4) {
                float x0 = xrow[4 * k4 + 0];
                float x1 = xrow[4 * k4 + 1];
                float x2 = xrow[4 * k4 + 2];
                float x3 = xrow[4 * k4 + 3];
                const float* wr = Wd + (size_t)(chunk * 64 + 4 * k4) * 64 + c0;
#pragma unroll
                for (int j = 0; j < 8; ++j) {
                    float a = acc[j];
                    a = fmaf(x0, wr[j],       a);
                    a = fmaf(x1, wr[64 + j],  a);
                    a = fmaf(x2, wr[128 + j], a);
                    a = fmaf(x3, wr[192 + j], a);
                    acc[j] = a;
                }
            }
        }
        __syncthreads();
#pragma unroll
        for (int j = 0; j < 8; ++j) xs[lane * 65 + c0 + j] = acc[j];
        __syncthreads();
        // coalesced store + fused BN partial (col = tid&63, constant per thread)
        float s = 0.f, q = 0.f;
        for (int i = tid; i < 4096; i += 512) {
            int r = i >> 6, c = i & 63;
            float v = xs[r * 65 + c];
            H[(size_t)(row0 + r) * 64 + c] = v;
            s += v; q += v * v;
        }
        __syncthreads();                         // xs free now
        float* red = xs;
        red[tid] = s; red[512 + tid] = q;
        __syncthreads();
        if (tid < 64) {
            float ss = 0.f, qq = 0.f;
#pragma unroll
            for (int gidx = 0; gidx < 8; ++gidx) {
                ss += red[gidx * 64 + tid];
                qq += red[512 + gidx * 64 + tid];
            }
            atomicAdd(&bnsum[tid], ss);
            atomicAdd(&bnsumsq[tid], qq);
        }
        return;
    }

    // ---- gather for bucket bb: 4 edges per VMEM instruction ----
    const int bb = blockIdx.x - DNNB;
    GatherSh& G = sh.g;
    const int g4 = lane >> 4;                    // edge sub-group 0..3
    const int l16 = lane & 15;                   // col-quad index
    if (tid < 64) {                              // wave 0: load hist + 64-wide scan
        G.w[tid] = 0.f;
        int v = cnth[bb * 64 + tid];
        G.cntS[tid] = v;
        int s = v;
#pragma unroll
        for (int o = 1; o < 64; o <<= 1) {
            int u = __shfl_up(s, o);
            if (lane >= o) s += u;
        }
        G.offsS[tid] = s - v;
        G.curS[tid] = s - v;
    }
    __syncthreads();
    // wraw accumulation from the row-bucket (dis is a 200 KB L2-resident table)
    const int n2 = gcurR[bb];
    const uint* srcR = bufR + (size_t)bb * BCAP;
    for (int i = tid; i < n2; i += 512) {
        uint e = srcR[i];
        atomicAdd(&G.w[e >> 16], dis[e & 0xffffu]);
    }
    // LDS counting-sort scatter of the col-bucket
    const int n = gcurC[bb];
    const uint* src = bufC + (size_t)bb * BCAP;
    for (int i = tid; i < n; i += 512) {
        uint e = src[i];
        int p = atomicAdd(&G.curS[e & 63u], 1);
        G.sorted[p] = (int)(e >> 6);
    }
    __syncthreads();
    // each wave: 8 consecutive nodes; 4 edges/instr, uint2 (4 fp16 cols)/lane
    float sacc0 = 0.f, sacc1 = 0.f, sacc2 = 0.f, sacc3 = 0.f;
    const float4 blv = *reinterpret_cast<const float4*>(b1 + (l16 << 2));
#pragma unroll 1
    for (int t = 0; t < 8; ++t) {
        const int nd = wv * 8 + t;
        const int lo = G.offsS[nd], hi2 = lo + G.cntS[nd];
        float a0 = 0.f, a1 = 0.f, a2 = 0.f, a3 = 0.f;
        for (int e = lo; e < hi2; e += 8) {
            int i0 = e + g4;
            int i1 = e + 4 + g4;
            int j0 = (i0 < hi2) ? i0 : hi2 - 1;
            int j1 = (i1 < hi2) ? i1 : hi2 - 1;
            float s0 = (i0 < hi2) ? 1.f : 0.f;
            float s1 = (i1 < hi2) ? 1.f : 0.f;
            int r0 = G.sorted[j0];
            int r1 = G.sorted[j1];
            uint2 v0 = *reinterpret_cast<const uint2*>(hs + ((size_t)r0 << 6) + (l16 << 2));
            uint2 v1 = *reinterpret_cast<const uint2*>(hs + ((size_t)r1 << 6) + (l16 << 2));
            a0 = fmaf(s0, h2f((ushort)(v0.x & 0xffffu)), a0);
            a1 = fmaf(s0, h2f((ushort)(v0.x >> 16)),     a1);
            a2 = fmaf(s0, h2f((ushort)(v0.y & 0xffffu)), a2);
            a3 = fmaf(s0, h2f((ushort)(v0.y >> 16)),     a3);
            a0 = fmaf(s1, h2f((ushort)(v1.x & 0xffffu)), a0);
            a1 = fmaf(s1, h2f((ushort)(v1.x >> 16)),     a1);
            a2 = fmaf(s1, h2f((ushort)(v1.y & 0xffffu)), a2);
            a3 = fmaf(s1, h2f((ushort)(v1.y >> 16)),     a3);
        }
        // combine the 4 edge sub-groups
        a0 += __shfl_xor(a0, 16); a0 += __shfl_xor(a0, 32);
        a1 += __shfl_xor(a1, 16); a1 += __shfl_xor(a1, 32);
        a2 += __shfl_xor(a2, 16); a2 += __shfl_xor(a2, 32);
        a3 += __shfl_xor(a3, 16); a3 += __shfl_xor(a3, 32);
        const int c = bb * 64 + nd;
        if (c < NN) {
            float d = dis[c];
            float coef = fmaf(d, G.w[nd], d * d);
            uint2 sv = *reinterpret_cast<const uint2*>(hs + ((size_t)c << 6) + (l16 << 2));
            float g0 = fmaf(d, a0 + h2f((ushort)(sv.x & 0xffffu)), blv.x);
            float g1 = fmaf(d, a1 + h2f((ushort)(sv.x >> 16)),     blv.y);
            float g2 = fmaf(d, a2 + h2f((ushort)(sv.y & 0xffffu)), blv.z);
            float g3 = fmaf(d, a3 + h2f((ushort)(sv.y >> 16)),     blv.w);
            sacc0 = fmaf(coef, fmaxf(g0, 0.f), sacc0);
            sacc1 = fmaf(coef, fmaxf(g1, 0.f), sacc1);
            sacc2 = fmaf(coef, fmaxf(g2, 0.f), sacc2);
            sacc3 = fmaf(coef, fmaxf(g3, 0.f), sacc3);
        }
    }
    if (g4 == 0) {
        G.red[wv][(l16 << 2) + 0] = sacc0;
        G.red[wv][(l16 << 2) + 1] = sacc1;
        G.red[wv][(l16 << 2) + 2] = sacc2;
        G.red[wv][(l16 << 2) + 3] = sacc3;
    }
    __syncthreads();
    if (wv == 0) {
        float s = ((G.red[0][lane] + G.red[1][lane]) + (G.red[2][lane] + G.red[3][lane])) +
                  ((G.red[4][lane] + G.red[5][lane]) + (G.red[6][lane] + G.red[7][lane]));
        atomicAdd(&svec[lane], s);
    }
}

// ---------------- output + fused finalize --------------------------------------
__global__ __launch_bounds__(256) void out_final(const float* __restrict__ H,
    const float* __restrict__ bnsum, const float* __restrict__ bnsumsq,
    const float* __restrict__ gamma, const float* __restrict__ beta,
    const float* __restrict__ svec, const float* __restrict__ g2W,
    const float* __restrict__ g2b, const float* __restrict__ fc1W,
    const float* __restrict__ fc1b, const float* __restrict__ fc2W,
    const float* __restrict__ fc2b, float* __restrict__ out)
{
    __shared__ float scaleS[64], shiftS[64], vdnnS[64];
    __shared__ float consS;
    const int tid = threadIdx.x;
    const int lane = tid & 63;
    const int grp = tid >> 6;
    if (tid < 64) {                              // wave 0 computes finalize
        int j = tid;
        float mu = bnsum[j] * (1.0f / NB);
        float var = bnsumsq[j] * (1.0f / NB) - mu * mu;
        float sc = rsqrtf(var + 1e-5f) * gamma[j];
        scaleS[j] = sc;
        shiftS[j] = beta[j] - mu * sc;
        float ge = 0.f;
        for (int k = 0; k < 64; ++k) ge += svec[k] * g2W[k * 64 + j];
        ge = ge * (1.0f / NN) + g2b[j];
        float vd = 0.f, vg = 0.f;
        for (int k = 0; k < 64; ++k) {
            vd += fc1W[j * 64 + k] * fc2W[k];
            vg += fc1W[(64 + j) * 64 + k] * fc2W[k];
        }
        vdnnS[j] = vd;
        float part = ge * vg + fc1b[j] * fc2W[j];
#pragma unroll
        for (int o = 32; o > 0; o >>= 1) part += __shfl_down(part, o);
        if (j == 0) consS = part + fc2b[0];
    }
    __syncthreads();
    const float sc = scaleS[lane], sh = shiftS[lane], vd = vdnnS[lane];
    const float C = consS;
#pragma unroll 1
    for (int t = 0; t < 8; ++t) {
        int i = blockIdx.x * 32 + grp * 8 + t;
        float x = H[(size_t)i * 64 + lane] * sc + sh;
        x = fmaxf(x, 0.f) * vd;
#pragma unroll
        for (int o = 32; o > 0; o >>= 1) x += __shfl_down(x, o);
        if (lane == 0) out[i] = x + C;
    }
}

extern "C" void kernel_launch(void* const* d_in, const int* in_sizes, int n_in,
                              void* d_out, int out_size, void* d_ws, size_t ws_size,
                              hipStream_t stream)
{
    const float* x1    = (const float*)d_in[0];
    const float* x2    = (const float*)d_in[1];
    const int*   ei    = (const int*)d_in[2];
    const float* dnnW  = (const float*)d_in[3];
    // d_in[4] = dnn_b: cancels inside BatchNorm, unused
    const float* gamma = (const float*)d_in[5];
    const float* beta  = (const float*)d_in[6];
    const float* g1W   = (const float*)d_in[7];
    const float* g1b   = (const float*)d_in[8];
    const float* g2W   = (const float*)d_in[9];
    const float* g2b   = (const float*)d_in[10];
    const float* fc1W  = (const float*)d_in[11];
    const float* fc1b  = (const float*)d_in[12];
    const float* fc2W  = (const float*)d_in[13];
    const float* fc2b  = (const float*)d_in[14];

    float* ws      = (float*)d_ws;
    ushort* h1h    = (ushort*)ws;                 // 50176*64 ushorts = 1,605,632 f
    float* hdnn    = ws + 1605632;                // 1,048,576 f
    float* dis     = hdnn + 1048576;              // 50,176 f
    int*   cnth    = (int*)(dis + 50176 + 25088); // 50,176 i (keeps old layout)
    uint*  bufC    = (uint*)(cnth + 50176);       // 784*1280 = 1,003,520
    uint*  bufR    = bufC + NBKT * BCAP;          // 1,003,520
    int*   gcurC   = (int*)(bufR + NBKT * BCAP);  // 784   <- zero region start
    int*   gcurR   = gcurC + NBKT;                // 784
    float* bnsum   = (float*)(gcurR + NBKT);      // 64
    float* bnsumsq = bnsum + 64;                  // 64
    float* svec    = bnsumsq + 64;                // 64    <- zero region end (1760)

    zero_kernel<<<1, 256, 0, stream>>>(gcurC, NBKT * 2 + 192);

    binCR<<<P1B, 512, 0, stream>>>(ei, bufC, bufR, gcurC, gcurR);
    gcn_gemm<<<NBKT, 256, 0, stream>>>(bufC, gcurC, x2, g1W, h1h, dis, cnth);
    gather_dnn<<<DNNB + NBKT, 512, 0, stream>>>(bufC, gcurC, cnth, bufR, gcurR,
                                                dis, h1h, g1b, svec,
                                                x1, dnnW, hdnn, bnsum, bnsumsq);
    out_final<<<512, 256, 0, stream>>>(hdnn, bnsum, bnsumsq, gamma, beta, svec,
                                       g2W, g2b, fc1W, fc1b, fc2W, fc2b,
                                       (float*)d_out);
}

// Round 17
// 106.072 us; speedup vs baseline: 1.2983x; 1.1085x over previous
//
#include <hip/hip_runtime.h>
#include <hip/hip_fp16.h>

#define NN 50000
#define NE 800000
#define NB 16384

#define NBKT 784          // buckets of 64 node ids (784*64 = 50176 >= NN)
#define BCAP 1280         // per-bucket capacity (mean 1020, +8 sigma)
#define CAPL 8            // LDS staging depth per bucket per binning block
#define P1B  256          // binning blocks
#define DNNB 256          // DNN gemm blocks (64 rows each)

typedef unsigned int uint;
typedef unsigned short ushort;

__device__ __forceinline__ uint pack2h(float a, float b) {
    return (uint)__half_as_ushort(__float2half_rn(a)) |
           ((uint)__half_as_ushort(__float2half_rn(b)) << 16);
}
__device__ __forceinline__ float h2f(ushort u) {
    return __half2float(__ushort_as_half(u));
}

// ---------------- zero the counters (runtime fill kernel is pathological) ------
__global__ void zero_kernel(int* __restrict__ p, int n)
{
    for (int i = threadIdx.x; i < n; i += 256) p[i] = 0;
}

// ---------------- megakernel: binCR + DNN GEMM(+BN) + GCN GEMM (unscaled) ------
// Blocks [0,256): binCR ; [256,512): DNN ; [512,1296): GCN1. All independent.
struct BinSh {
    uint stC[NBKT * CAPL];                      // 25 KiB
    uint stR[NBKT * CAPL];                      // 25 KiB
    int lcC[NBKT], lcR[NBKT];                   // 6.1 KiB
};
union MegaSh {
    BinSh b;                                    // ~56.4 KiB
    float xs[64 * 65];                          // 16.6 KiB (GEMM branches)
};

__global__ __launch_bounds__(512) void mega(const int* __restrict__ ei,
    uint* __restrict__ bufC, uint* __restrict__ bufR,
    int* __restrict__ gcurC, int* __restrict__ gcurR,
    const float* __restrict__ X1, const float* __restrict__ Wd,
    float* __restrict__ H, float* __restrict__ bnsum,
    float* __restrict__ bnsumsq,
    const float* __restrict__ X2, const float* __restrict__ W1,
    ushort* __restrict__ Hh)
{
    __shared__ MegaSh sh;
    const int tid = threadIdx.x;
    const int lane = tid & 63;
    const int wv = __builtin_amdgcn_readfirstlane(tid >> 6);   // 0..7

    if (blockIdx.x < P1B) {
        // ---- binCR: dual LDS-staged binning, one pass over ei ----
        BinSh& B = sh.b;
        for (int i = tid; i < NBKT; i += 512) { B.lcC[i] = 0; B.lcR[i] = 0; }
        __syncthreads();
        const int per = (NE + P1B - 1) / P1B;
        const int lo = blockIdx.x * per;
        const int hi = (lo + per < NE) ? lo + per : NE;
        for (int e = lo + tid; e < hi; e += 512) {
            int r = ei[e], c = ei[NE + e];
            uint entC = ((uint)r << 6) | (uint)(c & 63);
            int b = c >> 6;
            int pos = atomicAdd(&B.lcC[b], 1);
            if (pos < CAPL) B.stC[b * CAPL + pos] = entC;
            else { int gp = atomicAdd(&gcurC[b], 1); bufC[(size_t)b * BCAP + gp] = entC; }
            uint entR = ((uint)(r & 63) << 16) | (uint)c;
            int rb = r >> 6;
            int pos2 = atomicAdd(&B.lcR[rb], 1);
            if (pos2 < CAPL) B.stR[rb * CAPL + pos2] = entR;
            else { int gp = atomicAdd(&gcurR[rb], 1); bufR[(size_t)rb * BCAP + gp] = entR; }
        }
        __syncthreads();
        // coalesced flush: 8 buckets per wave iteration, 8 lanes per bucket
        for (int base = wv * 8; base < NBKT; base += 64) {
            int wb = base + (lane >> 3);
            int idx = lane & 7;
            int n = B.lcC[wb]; if (n > CAPL) n = CAPL;
            int gb = 0;
            if (idx == 0 && n > 0) gb = atomicAdd(&gcurC[wb], n);
            gb = __shfl(gb, lane & 56);
            if (idx < n) bufC[(size_t)wb * BCAP + gb + idx] = B.stC[wb * CAPL + idx];
            int n2 = B.lcR[wb]; if (n2 > CAPL) n2 = CAPL;
            int gb2 = 0;
            if (idx == 0 && n2 > 0) gb2 = atomicAdd(&gcurR[wb], n2);
            gb2 = __shfl(gb2, lane & 56);
            if (idx < n2) bufR[(size_t)wb * BCAP + gb2 + idx] = B.stR[wb * CAPL + idx];
        }
        return;
    }

    if (blockIdx.x < P1B + DNNB) {
        // ---- DNN: 64 rows, K=256 in 4 staged chunks, lane = row, 8 waves ----
        float* xs = sh.xs;
        const int c0 = wv * 8;
        const int row0 = (blockIdx.x - P1B) * 64;
        float acc[8];
#pragma unroll
        for (int j = 0; j < 8; ++j) acc[j] = 0.f;
#pragma unroll 1
        for (int chunk = 0; chunk < 4; ++chunk) {
            if (chunk) __syncthreads();
            for (int i = tid; i < 4096; i += 512) {
                int r = i >> 6, k = i & 63;
                xs[r * 65 + k] = X1[(size_t)(row0 + r) * 256 + chunk * 64 + k];
            }
            __syncthreads();
            const float* xrow = xs + lane * 65;
#pragma unroll
            for (int k4 = 0; k4 < 16; ++k4) {
                float x0 = xrow[4 * k4 + 0];
                float x1 = xrow[4 * k4 + 1];
                float x2 = xrow[4 * k4 + 2];
                float x3 = xrow[4 * k4 + 3];
                const float* wr = Wd + (size_t)(chunk * 64 + 4 * k4) * 64 + c0;
#pragma unroll
                for (int j = 0; j < 8; ++j) {
                    float a = acc[j];
                    a = fmaf(x0, wr[j],       a);
                    a = fmaf(x1, wr[64 + j],  a);
                    a = fmaf(x2, wr[128 + j], a);
                    a = fmaf(x3, wr[192 + j], a);
                    acc[j] = a;
                }
            }
        }
        __syncthreads();
#pragma unroll
        for (int j = 0; j < 8; ++j) xs[lane * 65 + c0 + j] = acc[j];
        __syncthreads();
        float s = 0.f, q = 0.f;
        for (int i = tid; i < 4096; i += 512) {
            int r = i >> 6, c = i & 63;
            float v = xs[r * 65 + c];
            H[(size_t)(row0 + r) * 64 + c] = v;
            s += v; q += v * v;
        }
        __syncthreads();
        float* red = xs;
        red[tid] = s; red[512 + tid] = q;
        __syncthreads();
        if (tid < 64) {
            float ss = 0.f, qq = 0.f;
#pragma unroll
            for (int gidx = 0; gidx < 8; ++gidx) {
                ss += red[gidx * 64 + tid];
                qq += red[512 + gidx * 64 + tid];
            }
            atomicAdd(&bnsum[tid], ss);
            atomicAdd(&bnsumsq[tid], qq);
        }
        return;
    }

    // ---- GCN1: h1h = fp16(x2 @ g1W) UNSCALED, K=64, lane = row, 8 waves ----
    {
        float* xs = sh.xs;
        const int c0 = wv * 8;
        const int row0 = (blockIdx.x - P1B - DNNB) * 64;
        float acc[8];
#pragma unroll
        for (int j = 0; j < 8; ++j) acc[j] = 0.f;
        if (row0 + 64 <= NN) {
            for (int i = tid; i < 4096; i += 512) {
                int r = i >> 6, k = i & 63;
                xs[r * 65 + k] = X2[(size_t)(row0 + r) * 64 + k];
            }
        } else {
            for (int i = tid; i < 4096; i += 512) {
                int r = i >> 6, k = i & 63;
                xs[r * 65 + k] = (row0 + r < NN)
                               ? X2[(size_t)(row0 + r) * 64 + k] : 0.f;
            }
        }
        __syncthreads();
        const float* xrow = xs + lane * 65;
#pragma unroll
        for (int k4 = 0; k4 < 16; ++k4) {
            float x0 = xrow[4 * k4 + 0];
            float x1 = xrow[4 * k4 + 1];
            float x2 = xrow[4 * k4 + 2];
            float x3 = xrow[4 * k4 + 3];
            const float* wr = W1 + (size_t)(4 * k4) * 64 + c0;
#pragma unroll
            for (int j = 0; j < 8; ++j) {
                float a = acc[j];
                a = fmaf(x0, wr[j],       a);
                a = fmaf(x1, wr[64 + j],  a);
                a = fmaf(x2, wr[128 + j], a);
                a = fmaf(x3, wr[192 + j], a);
                acc[j] = a;
            }
        }
        __syncthreads();
#pragma unroll
        for (int j = 0; j < 8; ++j) xs[lane * 65 + c0 + j] = acc[j];
        __syncthreads();
        for (int i = tid; i < 2048; i += 512) {
            int r = i >> 5, cp = (i & 31) * 2;
            int row = row0 + r;
            if (row < NN) {
                uint v = pack2h(xs[r * 65 + cp], xs[r * 65 + cp + 1]);
                *reinterpret_cast<uint*>(Hh + (size_t)row * 64 + cp) = v;
            }
        }
    }
}

// ---------------- per-bucket histogram -> dis, cnth; scale h1h rows in place ---
__global__ __launch_bounds__(256) void cnt_dis_scale(const uint* __restrict__ bufC,
    const int* __restrict__ gcurC, ushort* __restrict__ Hh,
    float* __restrict__ dis, int* __restrict__ cnth)
{
    __shared__ int hist[64];
    __shared__ float disS[64];
    const int tid = threadIdx.x, bb = blockIdx.x;
    const int row0 = bb * 64;
    if (tid < 64) hist[tid] = 0;
    __syncthreads();
    const int n = gcurC[bb];
    const uint* src = bufC + (size_t)bb * BCAP;
    for (int i = tid; i < n; i += 256) atomicAdd(&hist[src[i] & 63], 1);
    __syncthreads();
    if (tid < 64) {
        int c = row0 + tid;
        cnth[row0 + tid] = hist[tid];
        float d = rsqrtf((float)hist[tid] + 1.0f);
        disS[tid] = d;
        if (c < NN) dis[c] = d;
    }
    __syncthreads();
    // scale this block's 64 h1h rows by dis (block owns rows exclusively)
    for (int i = tid; i < 2048; i += 256) {
        int r = i >> 5, cp = (i & 31) * 2;
        int row = row0 + r;
        if (row < NN) {
            uint* p = reinterpret_cast<uint*>(Hh + (size_t)row * 64 + cp);
            uint v = *p;
            float d = disS[r];
            *p = pack2h(d * h2f((ushort)(v & 0xffffu)),
                        d * h2f((ushort)(v >> 16)));
        }
    }
}

// ---------------- gather (4 edges/VMEM-instr) + wraw + node epilogue -----------
__global__ __launch_bounds__(512) void gather_pass(const uint* __restrict__ bufC,
    const int* __restrict__ gcurC, const int* __restrict__ cnth,
    const uint* __restrict__ bufR, const int* __restrict__ gcurR,
    const float* __restrict__ dis, const ushort* __restrict__ hs,
    const float* __restrict__ b1, float* __restrict__ svec)
{
    __shared__ int sorted[BCAP];
    __shared__ int cntS[64], offsS[64], curS[64];
    __shared__ float w[64];
    __shared__ float red[8][64];
    const int tid = threadIdx.x;
    const int lane = tid & 63;
    const int wv = __builtin_amdgcn_readfirstlane(tid >> 6);   // 0..7
    const int bb = blockIdx.x;
    const int g4 = lane >> 4;                    // edge sub-group 0..3
    const int l16 = lane & 15;                   // col-quad index
    if (tid < 64) {                              // wave 0: load hist + 64-wide scan
        w[tid] = 0.f;
        int v = cnth[bb * 64 + tid];
        cntS[tid] = v;
        int s = v;
#pragma unroll
        for (int o = 1; o < 64; o <<= 1) {
            int u = __shfl_up(s, o);
            if (lane >= o) s += u;
        }
        offsS[tid] = s - v;
        curS[tid] = s - v;
    }
    __syncthreads();
    // wraw accumulation from the row-bucket (dis is a 200 KB L2-resident table)
    const int n2 = gcurR[bb];
    const uint* srcR = bufR + (size_t)bb * BCAP;
    for (int i = tid; i < n2; i += 512) {
        uint e = srcR[i];
        atomicAdd(&w[e >> 16], dis[e & 0xffffu]);
    }
    // LDS counting-sort scatter of the col-bucket
    const int n = gcurC[bb];
    const uint* src = bufC + (size_t)bb * BCAP;
    for (int i = tid; i < n; i += 512) {
        uint e = src[i];
        int p = atomicAdd(&curS[e & 63u], 1);
        sorted[p] = (int)(e >> 6);
    }
    __syncthreads();
    // each wave: 8 consecutive nodes; 4 edges/instr, uint2 (4 fp16 cols)/lane
    float sacc0 = 0.f, sacc1 = 0.f, sacc2 = 0.f, sacc3 = 0.f;
    const float4 blv = *reinterpret_cast<const float4*>(b1 + (l16 << 2));
#pragma unroll 1
    for (int t = 0; t < 8; ++t) {
        const int nd = wv * 8 + t;
        const int lo = offsS[nd], hi2 = lo + cntS[nd];
        float a0 = 0.f, a1 = 0.f, a2 = 0.f, a3 = 0.f;
        for (int e = lo; e < hi2; e += 8) {
            int i0 = e + g4;
            int i1 = e + 4 + g4;
            int j0 = (i0 < hi2) ? i0 : hi2 - 1;
            int j1 = (i1 < hi2) ? i1 : hi2 - 1;
            float s0 = (i0 < hi2) ? 1.f : 0.f;
            float s1 = (i1 < hi2) ? 1.f : 0.f;
            int r0 = sorted[j0];
            int r1 = sorted[j1];
            uint2 v0 = *reinterpret_cast<const uint2*>(hs + ((size_t)r0 << 6) + (l16 << 2));
            uint2 v1 = *reinterpret_cast<const uint2*>(hs + ((size_t)r1 << 6) + (l16 << 2));
            a0 = fmaf(s0, h2f((ushort)(v0.x & 0xffffu)), a0);
            a1 = fmaf(s0, h2f((ushort)(v0.x >> 16)),     a1);
            a2 = fmaf(s0, h2f((ushort)(v0.y & 0xffffu)), a2);
            a3 = fmaf(s0, h2f((ushort)(v0.y >> 16)),     a3);
            a0 = fmaf(s1, h2f((ushort)(v1.x & 0xffffu)), a0);
            a1 = fmaf(s1, h2f((ushort)(v1.x >> 16)),     a1);
            a2 = fmaf(s1, h2f((ushort)(v1.y & 0xffffu)), a2);
            a3 = fmaf(s1, h2f((ushort)(v1.y >> 16)),     a3);
        }
        a0 += __shfl_xor(a0, 16); a0 += __shfl_xor(a0, 32);
        a1 += __shfl_xor(a1, 16); a1 += __shfl_xor(a1, 32);
        a2 += __shfl_xor(a2, 16); a2 += __shfl_xor(a2, 32);
        a3 += __shfl_xor(a3, 16); a3 += __shfl_xor(a3, 32);
        const int c = bb * 64 + nd;
        if (c < NN) {
            float d = dis[c];
            float coef = fmaf(d, w[nd], d * d);
            uint2 sv = *reinterpret_cast<const uint2*>(hs + ((size_t)c << 6) + (l16 << 2));
            float g0 = fmaf(d, a0 + h2f((ushort)(sv.x & 0xffffu)), blv.x);
            float g1 = fmaf(d, a1 + h2f((ushort)(sv.x >> 16)),     blv.y);
            float g2 = fmaf(d, a2 + h2f((ushort)(sv.y & 0xffffu)), blv.z);
            float g3 = fmaf(d, a3 + h2f((ushort)(sv.y >> 16)),     blv.w);
            sacc0 = fmaf(coef, fmaxf(g0, 0.f), sacc0);
            sacc1 = fmaf(coef, fmaxf(g1, 0.f), sacc1);
            sacc2 = fmaf(coef, fmaxf(g2, 0.f), sacc2);
            sacc3 = fmaf(coef, fmaxf(g3, 0.f), sacc3);
        }
    }
    if (g4 == 0) {
        red[wv][(l16 << 2) + 0] = sacc0;
        red[wv][(l16 << 2) + 1] = sacc1;
        red[wv][(l16 << 2) + 2] = sacc2;
        red[wv][(l16 << 2) + 3] = sacc3;
    }
    __syncthreads();
    if (wv == 0) {
        float s = ((red[0][lane] + red[1][lane]) + (red[2][lane] + red[3][lane])) +
                  ((red[4][lane] + red[5][lane]) + (red[6][lane] + red[7][lane]));
        atomicAdd(&svec[lane], s);
    }
}

// ---------------- output + fused finalize --------------------------------------
__global__ __launch_bounds__(256) void out_final(const float* __restrict__ H,
    const float* __restrict__ bnsum, const float* __restrict__ bnsumsq,
    const float* __restrict__ gamma, const float* __restrict__ beta,
    const float* __restrict__ svec, const float* __restrict__ g2W,
    const float* __restrict__ g2b, const float* __restrict__ fc1W,
    const float* __restrict__ fc1b, const float* __restrict__ fc2W,
    const float* __restrict__ fc2b, float* __restrict__ out)
{
    __shared__ float scaleS[64], shiftS[64], vdnnS[64];
    __shared__ float consS;
    const int tid = threadIdx.x;
    const int lane = tid & 63;
    const int grp = tid >> 6;
    if (tid < 64) {                              // wave 0 computes finalize
        int j = tid;
        float mu = bnsum[j] * (1.0f / NB);
        float var = bnsumsq[j] * (1.0f / NB) - mu * mu;
        float sc = rsqrtf(var + 1e-5f) * gamma[j];
        scaleS[j] = sc;
        shiftS[j] = beta[j] - mu * sc;
        float ge = 0.f;
        for (int k = 0; k < 64; ++k) ge += svec[k] * g2W[k * 64 + j];
        ge = ge * (1.0f / NN) + g2b[j];
        float vd = 0.f, vg = 0.f;
        for (int k = 0; k < 64; ++k) {
            vd += fc1W[j * 64 + k] * fc2W[k];
            vg += fc1W[(64 + j) * 64 + k] * fc2W[k];
        }
        vdnnS[j] = vd;
        float part = ge * vg + fc1b[j] * fc2W[j];
#pragma unroll
        for (int o = 32; o > 0; o >>= 1) part += __shfl_down(part, o);
        if (j == 0) consS = part + fc2b[0];
    }
    __syncthreads();
    const float sc = scaleS[lane], sh = shiftS[lane], vd = vdnnS[lane];
    const float C = consS;
#pragma unroll 1
    for (int t = 0; t < 8; ++t) {
        int i = blockIdx.x * 32 + grp * 8 + t;
        float x = H[(size_t)i * 64 + lane] * sc + sh;
        x = fmaxf(x, 0.f) * vd;
#pragma unroll
        for (int o = 32; o > 0; o >>= 1) x += __shfl_down(x, o);
        if (lane == 0) out[i] = x + C;
    }
}

extern "C" void kernel_launch(void* const* d_in, const int* in_sizes, int n_in,
                              void* d_out, int out_size, void* d_ws, size_t ws_size,
                              hipStream_t stream)
{
    const float* x1    = (const float*)d_in[0];
    const float* x2    = (const float*)d_in[1];
    const int*   ei    = (const int*)d_in[2];
    const float* dnnW  = (const float*)d_in[3];
    // d_in[4] = dnn_b: cancels inside BatchNorm, unused
    const float* gamma = (const float*)d_in[5];
    const float* beta  = (const float*)d_in[6];
    const float* g1W   = (const float*)d_in[7];
    const float* g1b   = (const float*)d_in[8];
    const float* g2W   = (const float*)d_in[9];
    const float* g2b   = (const float*)d_in[10];
    const float* fc1W  = (const float*)d_in[11];
    const float* fc1b  = (const float*)d_in[12];
    const float* fc2W  = (const float*)d_in[13];
    const float* fc2b  = (const float*)d_in[14];

    float* ws      = (float*)d_ws;
    ushort* h1h    = (ushort*)ws;                 // 50176*64 ushorts = 1,605,632 f
    float* hdnn    = ws + 1605632;                // 1,048,576 f
    float* dis     = hdnn + 1048576;              // 50,176 f
    int*   cnth    = (int*)(dis + 50176 + 25088); // 50,176 i (keeps old layout)
    uint*  bufC    = (uint*)(cnth + 50176);       // 784*1280 = 1,003,520
    uint*  bufR    = bufC + NBKT * BCAP;          // 1,003,520
    int*   gcurC   = (int*)(bufR + NBKT * BCAP);  // 784   <- zero region start
    int*   gcurR   = gcurC + NBKT;                // 784
    float* bnsum   = (float*)(gcurR + NBKT);      // 64
    float* bnsumsq = bnsum + 64;                  // 64
    float* svec    = bnsumsq + 64;                // 64    <- zero region end (1760)

    zero_kernel<<<1, 256, 0, stream>>>(gcurC, NBKT * 2 + 192);

    mega<<<P1B + DNNB + NBKT, 512, 0, stream>>>(ei, bufC, bufR, gcurC, gcurR,
                                                x1, dnnW, hdnn, bnsum, bnsumsq,
                                                x2, g1W, h1h);
    cnt_dis_scale<<<NBKT, 256, 0, stream>>>(bufC, gcurC, h1h, dis, cnth);
    gather_pass<<<NBKT, 512, 0, stream>>>(bufC, gcurC, cnth, bufR, gcurR,
                                          dis, h1h, g1b, svec);
    out_final<<<512, 256, 0, stream>>>(hdnn, bnsum, bnsumsq, gamma, beta, svec,
                                       g2W, g2b, fc1W, fc1b, fc2W, fc2b,
                                       (float*)d_out);
}

// Round 18
// 103.583 us; speedup vs baseline: 1.3295x; 1.0240x over previous
//
#include <hip/hip_runtime.h>
#include <hip/hip_fp16.h>

#define NN 50000
#define NE 800000
#define NB 16384

#define NBKT 784          // buckets of 64 node ids (784*64 = 50176 >= NN)
#define BCAP 1280         // per-bucket capacity (mean 1020, +8 sigma)
#define CAPL 8            // LDS staging depth per bucket per binning block
#define P1B  256          // binning blocks
#define DNNB 256          // DNN gemm blocks (64 rows each)

typedef unsigned int uint;
typedef unsigned short ushort;

__device__ __forceinline__ uint pack2h(float a, float b) {
    return (uint)__half_as_ushort(__float2half_rn(a)) |
           ((uint)__half_as_ushort(__float2half_rn(b)) << 16);
}
__device__ __forceinline__ float h2f(ushort u) {
    return __half2float(__ushort_as_half(u));
}

// ---------------- zero the counters (runtime fill kernel is pathological) ------
__global__ void zero_kernel(int* __restrict__ p, int n)
{
    for (int i = threadIdx.x; i < n; i += 256) p[i] = 0;
}

// ---------------- megakernel: bin (2-pass) + DNN GEMM(+BN) + GCN GEMM ----------
// Blocks [0,256): binning ; [256,512): DNN ; [512,1296): GCN1. All independent.
// Bin branch stages C then R through ONE 25 KiB buffer (two passes over ei)
// so the union stays at 28.2 KiB -> 4-5 blocks/CU for every branch.
struct BinSh {
    uint st[NBKT * CAPL];                       // 25 KiB
    int lc[NBKT];                               // 3.1 KiB
};
union MegaSh {
    BinSh b;                                    // 28.2 KiB
    float xs[64 * 65];                          // 16.6 KiB (GEMM branches)
};

__global__ __launch_bounds__(512) void mega(const int* __restrict__ ei,
    uint* __restrict__ bufC, uint* __restrict__ bufR,
    int* __restrict__ gcurC, int* __restrict__ gcurR,
    const float* __restrict__ X1, const float* __restrict__ Wd,
    float* __restrict__ H, float* __restrict__ bnsum,
    float* __restrict__ bnsumsq,
    const float* __restrict__ X2, const float* __restrict__ W1,
    ushort* __restrict__ Hh)
{
    __shared__ MegaSh sh;
    const int tid = threadIdx.x;
    const int lane = tid & 63;
    const int wv = __builtin_amdgcn_readfirstlane(tid >> 6);   // 0..7

    if (blockIdx.x < P1B) {
        BinSh& B = sh.b;
        const int per = (NE + P1B - 1) / P1B;
        const int lo = blockIdx.x * per;
        const int hi = (lo + per < NE) ? lo + per : NE;
        // ---- pass 1: bin by col>>6, ent = (r<<6)|(c&63) ----
        for (int i = tid; i < NBKT; i += 512) B.lc[i] = 0;
        __syncthreads();
        for (int e = lo + tid; e < hi; e += 512) {
            int r = ei[e], c = ei[NE + e];
            uint ent = ((uint)r << 6) | (uint)(c & 63);
            int b = c >> 6;
            int pos = atomicAdd(&B.lc[b], 1);
            if (pos < CAPL) B.st[b * CAPL + pos] = ent;
            else { int gp = atomicAdd(&gcurC[b], 1); bufC[(size_t)b * BCAP + gp] = ent; }
        }
        __syncthreads();
        for (int base = wv * 8; base < NBKT; base += 64) {
            int wb = base + (lane >> 3);
            int idx = lane & 7;
            int n = B.lc[wb]; if (n > CAPL) n = CAPL;
            int gb = 0;
            if (idx == 0 && n > 0) gb = atomicAdd(&gcurC[wb], n);
            gb = __shfl(gb, lane & 56);
            if (idx < n) bufC[(size_t)wb * BCAP + gb + idx] = B.st[wb * CAPL + idx];
        }
        __syncthreads();
        // ---- pass 2: bin by row>>6, ent = ((r&63)<<16)|c ----
        for (int i = tid; i < NBKT; i += 512) B.lc[i] = 0;
        __syncthreads();
        for (int e = lo + tid; e < hi; e += 512) {
            int r = ei[e], c = ei[NE + e];
            uint ent = ((uint)(r & 63) << 16) | (uint)c;
            int rb = r >> 6;
            int pos = atomicAdd(&B.lc[rb], 1);
            if (pos < CAPL) B.st[rb * CAPL + pos] = ent;
            else { int gp = atomicAdd(&gcurR[rb], 1); bufR[(size_t)rb * BCAP + gp] = ent; }
        }
        __syncthreads();
        for (int base = wv * 8; base < NBKT; base += 64) {
            int wb = base + (lane >> 3);
            int idx = lane & 7;
            int n = B.lc[wb]; if (n > CAPL) n = CAPL;
            int gb = 0;
            if (idx == 0 && n > 0) gb = atomicAdd(&gcurR[wb], n);
            gb = __shfl(gb, lane & 56);
            if (idx < n) bufR[(size_t)wb * BCAP + gb + idx] = B.st[wb * CAPL + idx];
        }
        return;
    }

    if (blockIdx.x < P1B + DNNB) {
        // ---- DNN: 64 rows, K=256 in 4 staged chunks, lane = row, 8 waves ----
        float* xs = sh.xs;
        const int c0 = wv * 8;
        const int row0 = (blockIdx.x - P1B) * 64;
        float acc[8];
#pragma unroll
        for (int j = 0; j < 8; ++j) acc[j] = 0.f;
#pragma unroll 1
        for (int chunk = 0; chunk < 4; ++chunk) {
            if (chunk) __syncthreads();
            for (int i = tid; i < 4096; i += 512) {
                int r = i >> 6, k = i & 63;
                xs[r * 65 + k] = X1[(size_t)(row0 + r) * 256 + chunk * 64 + k];
            }
            __syncthreads();
            const float* xrow = xs + lane * 65;
#pragma unroll
            for (int k4 = 0; k4 < 16; ++k4) {
                float x0 = xrow[4 * k4 + 0];
                float x1 = xrow[4 * k4 + 1];
                float x2 = xrow[4 * k4 + 2];
                float x3 = xrow[4 * k4 + 3];
                const float* wr = Wd + (size_t)(chunk * 64 + 4 * k4) * 64 + c0;
#pragma unroll
                for (int j = 0; j < 8; ++j) {
                    float a = acc[j];
                    a = fmaf(x0, wr[j],       a);
                    a = fmaf(x1, wr[64 + j],  a);
                    a = fmaf(x2, wr[128 + j], a);
                    a = fmaf(x3, wr[192 + j], a);
                    acc[j] = a;
                }
            }
        }
        __syncthreads();
#pragma unroll
        for (int j = 0; j < 8; ++j) xs[lane * 65 + c0 + j] = acc[j];
        __syncthreads();
        float s = 0.f, q = 0.f;
        for (int i = tid; i < 4096; i += 512) {
            int r = i >> 6, c = i & 63;
            float v = xs[r * 65 + c];
            H[(size_t)(row0 + r) * 64 + c] = v;
            s += v; q += v * v;
        }
        __syncthreads();
        float* red = xs;
        red[tid] = s; red[512 + tid] = q;
        __syncthreads();
        if (tid < 64) {
            float ss = 0.f, qq = 0.f;
#pragma unroll
            for (int gidx = 0; gidx < 8; ++gidx) {
                ss += red[gidx * 64 + tid];
                qq += red[512 + gidx * 64 + tid];
            }
            atomicAdd(&bnsum[tid], ss);
            atomicAdd(&bnsumsq[tid], qq);
        }
        return;
    }

    // ---- GCN1: h1h = fp16(x2 @ g1W) UNSCALED, K=64, lane = row, 8 waves ----
    {
        float* xs = sh.xs;
        const int c0 = wv * 8;
        const int row0 = (blockIdx.x - P1B - DNNB) * 64;
        float acc[8];
#pragma unroll
        for (int j = 0; j < 8; ++j) acc[j] = 0.f;
        if (row0 + 64 <= NN) {
            for (int i = tid; i < 4096; i += 512) {
                int r = i >> 6, k = i & 63;
                xs[r * 65 + k] = X2[(size_t)(row0 + r) * 64 + k];
            }
        } else {
            for (int i = tid; i < 4096; i += 512) {
                int r = i >> 6, k = i & 63;
                xs[r * 65 + k] = (row0 + r < NN)
                               ? X2[(size_t)(row0 + r) * 64 + k] : 0.f;
            }
        }
        __syncthreads();
        const float* xrow = xs + lane * 65;
#pragma unroll
        for (int k4 = 0; k4 < 16; ++k4) {
            float x0 = xrow[4 * k4 + 0];
            float x1 = xrow[4 * k4 + 1];
            float x2 = xrow[4 * k4 + 2];
            float x3 = xrow[4 * k4 + 3];
            const float* wr = W1 + (size_t)(4 * k4) * 64 + c0;
#pragma unroll
            for (int j = 0; j < 8; ++j) {
                float a = acc[j];
                a = fmaf(x0, wr[j],       a);
                a = fmaf(x1, wr[64 + j],  a);
                a = fmaf(x2, wr[128 + j], a);
                a = fmaf(x3, wr[192 + j], a);
                acc[j] = a;
            }
        }
        __syncthreads();
#pragma unroll
        for (int j = 0; j < 8; ++j) xs[lane * 65 + c0 + j] = acc[j];
        __syncthreads();
        for (int i = tid; i < 2048; i += 512) {
            int r = i >> 5, cp = (i & 31) * 2;
            int row = row0 + r;
            if (row < NN) {
                uint v = pack2h(xs[r * 65 + cp], xs[r * 65 + cp + 1]);
                *reinterpret_cast<uint*>(Hh + (size_t)row * 64 + cp) = v;
            }
        }
    }
}

// ---------------- per-bucket histogram -> dis, cnth; scale h1h rows in place ---
__global__ __launch_bounds__(256) void cnt_dis_scale(const uint* __restrict__ bufC,
    const int* __restrict__ gcurC, ushort* __restrict__ Hh,
    float* __restrict__ dis, int* __restrict__ cnth)
{
    __shared__ int hist[64];
    __shared__ float disS[64];
    const int tid = threadIdx.x, bb = blockIdx.x;
    const int row0 = bb * 64;
    if (tid < 64) hist[tid] = 0;
    __syncthreads();
    const int n = gcurC[bb];
    const uint* src = bufC + (size_t)bb * BCAP;
    for (int i = tid; i < n; i += 256) atomicAdd(&hist[src[i] & 63], 1);
    __syncthreads();
    if (tid < 64) {
        int c = row0 + tid;
        cnth[row0 + tid] = hist[tid];
        float d = rsqrtf((float)hist[tid] + 1.0f);
        disS[tid] = d;
        if (c < NN) dis[c] = d;
    }
    __syncthreads();
    // scale this block's 64 h1h rows by dis (block owns rows exclusively)
    for (int i = tid; i < 2048; i += 256) {
        int r = i >> 5, cp = (i & 31) * 2;
        int row = row0 + r;
        if (row < NN) {
            uint* p = reinterpret_cast<uint*>(Hh + (size_t)row * 64 + cp);
            uint v = *p;
            float d = disS[r];
            *p = pack2h(d * h2f((ushort)(v & 0xffffu)),
                        d * h2f((ushort)(v >> 16)));
        }
    }
}

// ---------------- gather (4 edges/VMEM-instr) + wraw + node epilogue -----------
__global__ __launch_bounds__(512) void gather_pass(const uint* __restrict__ bufC,
    const int* __restrict__ gcurC, const int* __restrict__ cnth,
    const uint* __restrict__ bufR, const int* __restrict__ gcurR,
    const float* __restrict__ dis, const ushort* __restrict__ hs,
    const float* __restrict__ b1, float* __restrict__ svec)
{
    __shared__ int sorted[BCAP];
    __shared__ int cntS[64], offsS[64], curS[64];
    __shared__ float w[64];
    __shared__ float red[8][64];
    const int tid = threadIdx.x;
    const int lane = tid & 63;
    const int wv = __builtin_amdgcn_readfirstlane(tid >> 6);   // 0..7
    const int bb = blockIdx.x;
    const int g4 = lane >> 4;                    // edge sub-group 0..3
    const int l16 = lane & 15;                   // col-quad index
    if (tid < 64) {                              // wave 0: load hist + 64-wide scan
        w[tid] = 0.f;
        int v = cnth[bb * 64 + tid];
        cntS[tid] = v;
        int s = v;
#pragma unroll
        for (int o = 1; o < 64; o <<= 1) {
            int u = __shfl_up(s, o);
            if (lane >= o) s += u;
        }
        offsS[tid] = s - v;
        curS[tid] = s - v;
    }
    __syncthreads();
    // wraw accumulation from the row-bucket (dis is a 200 KB L2-resident table)
    const int n2 = gcurR[bb];
    const uint* srcR = bufR + (size_t)bb * BCAP;
    for (int i = tid; i < n2; i += 512) {
        uint e = srcR[i];
        atomicAdd(&w[e >> 16], dis[e & 0xffffu]);
    }
    // LDS counting-sort scatter of the col-bucket
    const int n = gcurC[bb];
    const uint* src = bufC + (size_t)bb * BCAP;
    for (int i = tid; i < n; i += 512) {
        uint e = src[i];
        int p = atomicAdd(&curS[e & 63u], 1);
        sorted[p] = (int)(e >> 6);
    }
    __syncthreads();
    // each wave: 8 consecutive nodes; 4 edges/instr, uint2 (4 fp16 cols)/lane
    float sacc0 = 0.f, sacc1 = 0.f, sacc2 = 0.f, sacc3 = 0.f;
    const float4 blv = *reinterpret_cast<const float4*>(b1 + (l16 << 2));
#pragma unroll 1
    for (int t = 0; t < 8; ++t) {
        const int nd = wv * 8 + t;
        const int lo = offsS[nd], hi2 = lo + cntS[nd];
        float a0 = 0.f, a1 = 0.f, a2 = 0.f, a3 = 0.f;
        for (int e = lo; e < hi2; e += 8) {
            int i0 = e + g4;
            int i1 = e + 4 + g4;
            int j0 = (i0 < hi2) ? i0 : hi2 - 1;
            int j1 = (i1 < hi2) ? i1 : hi2 - 1;
            float s0 = (i0 < hi2) ? 1.f : 0.f;
            float s1 = (i1 < hi2) ? 1.f : 0.f;
            int r0 = sorted[j0];
            int r1 = sorted[j1];
            uint2 v0 = *reinterpret_cast<const uint2*>(hs + ((size_t)r0 << 6) + (l16 << 2));
            uint2 v1 = *reinterpret_cast<const uint2*>(hs + ((size_t)r1 << 6) + (l16 << 2));
            a0 = fmaf(s0, h2f((ushort)(v0.x & 0xffffu)), a0);
            a1 = fmaf(s0, h2f((ushort)(v0.x >> 16)),     a1);
            a2 = fmaf(s0, h2f((ushort)(v0.y & 0xffffu)), a2);
            a3 = fmaf(s0, h2f((ushort)(v0.y >> 16)),     a3);
            a0 = fmaf(s1, h2f((ushort)(v1.x & 0xffffu)), a0);
            a1 = fmaf(s1, h2f((ushort)(v1.x >> 16)),     a1);
            a2 = fmaf(s1, h2f((ushort)(v1.y & 0xffffu)), a2);
            a3 = fmaf(s1, h2f((ushort)(v1.y >> 16)),     a3);
        }
        a0 += __shfl_xor(a0, 16); a0 += __shfl_xor(a0, 32);
        a1 += __shfl_xor(a1, 16); a1 += __shfl_xor(a1, 32);
        a2 += __shfl_xor(a2, 16); a2 += __shfl_xor(a2, 32);
        a3 += __shfl_xor(a3, 16); a3 += __shfl_xor(a3, 32);
        const int c = bb * 64 + nd;
        if (c < NN) {
            float d = dis[c];
            float coef = fmaf(d, w[nd], d * d);
            uint2 sv = *reinterpret_cast<const uint2*>(hs + ((size_t)c << 6) + (l16 << 2));
            float g0 = fmaf(d, a0 + h2f((ushort)(sv.x & 0xffffu)), blv.x);
            float g1 = fmaf(d, a1 + h2f((ushort)(sv.x >> 16)),     blv.y);
            float g2 = fmaf(d, a2 + h2f((ushort)(sv.y & 0xffffu)), blv.z);
            float g3 = fmaf(d, a3 + h2f((ushort)(sv.y >> 16)),     blv.w);
            sacc0 = fmaf(coef, fmaxf(g0, 0.f), sacc0);
            sacc1 = fmaf(coef, fmaxf(g1, 0.f), sacc1);
            sacc2 = fmaf(coef, fmaxf(g2, 0.f), sacc2);
            sacc3 = fmaf(coef, fmaxf(g3, 0.f), sacc3);
        }
    }
    if (g4 == 0) {
        red[wv][(l16 << 2) + 0] = sacc0;
        red[wv][(l16 << 2) + 1] = sacc1;
        red[wv][(l16 << 2) + 2] = sacc2;
        red[wv][(l16 << 2) + 3] = sacc3;
    }
    __syncthreads();
    if (wv == 0) {
        float s = ((red[0][lane] + red[1][lane]) + (red[2][lane] + red[3][lane])) +
                  ((red[4][lane] + red[5][lane]) + (red[6][lane] + red[7][lane]));
        atomicAdd(&svec[lane], s);
    }
}

// ---------------- output + fused finalize --------------------------------------
__global__ __launch_bounds__(256) void out_final(const float* __restrict__ H,
    const float* __restrict__ bnsum, const float* __restrict__ bnsumsq,
    const float* __restrict__ gamma, const float* __restrict__ beta,
    const float* __restrict__ svec, const float* __restrict__ g2W,
    const float* __restrict__ g2b, const float* __restrict__ fc1W,
    const float* __restrict__ fc1b, const float* __restrict__ fc2W,
    const float* __restrict__ fc2b, float* __restrict__ out)
{
    __shared__ float scaleS[64], shiftS[64], vdnnS[64];
    __shared__ float consS;
    const int tid = threadIdx.x;
    const int lane = tid & 63;
    const int grp = tid >> 6;
    if (tid < 64) {                              // wave 0 computes finalize
        int j = tid;
        float mu = bnsum[j] * (1.0f / NB);
        float var = bnsumsq[j] * (1.0f / NB) - mu * mu;
        float sc = rsqrtf(var + 1e-5f) * gamma[j];
        scaleS[j] = sc;
        shiftS[j] = beta[j] - mu * sc;
        float ge = 0.f;
        for (int k = 0; k < 64; ++k) ge += svec[k] * g2W[k * 64 + j];
        ge = ge * (1.0f / NN) + g2b[j];
        float vd = 0.f, vg = 0.f;
        for (int k = 0; k < 64; ++k) {
            vd += fc1W[j * 64 + k] * fc2W[k];
            vg += fc1W[(64 + j) * 64 + k] * fc2W[k];
        }
        vdnnS[j] = vd;
        float part = ge * vg + fc1b[j] * fc2W[j];
#pragma unroll
        for (int o = 32; o > 0; o >>= 1) part += __shfl_down(part, o);
        if (j == 0) consS = part + fc2b[0];
    }
    __syncthreads();
    const float sc = scaleS[lane], sh = shiftS[lane], vd = vdnnS[lane];
    const float C = consS;
#pragma unroll 1
    for (int t = 0; t < 8; ++t) {
        int i = blockIdx.x * 32 + grp * 8 + t;
        float x = H[(size_t)i * 64 + lane] * sc + sh;
        x = fmaxf(x, 0.f) * vd;
#pragma unroll
        for (int o = 32; o > 0; o >>= 1) x += __shfl_down(x, o);
        if (lane == 0) out[i] = x + C;
    }
}

extern "C" void kernel_launch(void* const* d_in, const int* in_sizes, int n_in,
                              void* d_out, int out_size, void* d_ws, size_t ws_size,
                              hipStream_t stream)
{
    const float* x1    = (const float*)d_in[0];
    const float* x2    = (const float*)d_in[1];
    const int*   ei    = (const int*)d_in[2];
    const float* dnnW  = (const float*)d_in[3];
    // d_in[4] = dnn_b: cancels inside BatchNorm, unused
    const float* gamma = (const float*)d_in[5];
    const float* beta  = (const float*)d_in[6];
    const float* g1W   = (const float*)d_in[7];
    const float* g1b   = (const float*)d_in[8];
    const float* g2W   = (const float*)d_in[9];
    const float* g2b   = (const float*)d_in[10];
    const float* fc1W  = (const float*)d_in[11];
    const float* fc1b  = (const float*)d_in[12];
    const float* fc2W  = (const float*)d_in[13];
    const float* fc2b  = (const float*)d_in[14];

    float* ws      = (float*)d_ws;
    ushort* h1h    = (ushort*)ws;                 // 50176*64 ushorts = 1,605,632 f
    float* hdnn    = ws + 1605632;                // 1,048,576 f
    float* dis     = hdnn + 1048576;              // 50,176 f
    int*   cnth    = (int*)(dis + 50176 + 25088); // 50,176 i (keeps old layout)
    uint*  bufC    = (uint*)(cnth + 50176);       // 784*1280 = 1,003,520
    uint*  bufR    = bufC + NBKT * BCAP;          // 1,003,520
    int*   gcurC   = (int*)(bufR + NBKT * BCAP);  // 784   <- zero region start
    int*   gcurR   = gcurC + NBKT;                // 784
    float* bnsum   = (float*)(gcurR + NBKT);      // 64
    float* bnsumsq = bnsum + 64;                  // 64
    float* svec    = bnsumsq + 64;                // 64    <- zero region end (1760)

    zero_kernel<<<1, 256, 0, stream>>>(gcurC, NBKT * 2 + 192);

    mega<<<P1B + DNNB + NBKT, 512, 0, stream>>>(ei, bufC, bufR, gcurC, gcurR,
                                                x1, dnnW, hdnn, bnsum, bnsumsq,
                                                x2, g1W, h1h);
    cnt_dis_scale<<<NBKT, 256, 0, stream>>>(bufC, gcurC, h1h, dis, cnth);
    gather_pass<<<NBKT, 512, 0, stream>>>(bufC, gcurC, cnth, bufR, gcurR,
                                          dis, h1h, g1b, svec);
    out_final<<<512, 256, 0, stream>>>(hdnn, bnsum, bnsumsq, gamma, beta, svec,
                                       g2W, g2b, fc1W, fc1b, fc2W, fc2b,
                                       (float*)d_out);
}